// Round 1
// baseline (2216.812 us; speedup 1.0000x reference)
//
#include <hip/hip_runtime.h>

// ---------------------------------------------------------------------------
// 2-layer LSTM (B=256,T=1024,in=64,H=128) + FC(128->32), bf16 MFMA compute.
// Batch-partitioned scan: 16 blocks x 16 rows, no inter-block sync.
// ---------------------------------------------------------------------------

static constexpr int B  = 256;
static constexpr int T  = 1024;
static constexpr int H  = 128;   // hidden
static constexpr int O  = 32;    // fc output

typedef __attribute__((ext_vector_type(8))) short  short8;
typedef __attribute__((ext_vector_type(4))) float  f32x4;

#define LOG2E 1.4426950408889634f

#if __has_builtin(__builtin_amdgcn_exp2f)
#define EXP2(x) __builtin_amdgcn_exp2f(x)
#else
#define EXP2(x) __expf((x) * 0.69314718056f)
#endif
#if __has_builtin(__builtin_amdgcn_rcpf)
#define RCP(x) __builtin_amdgcn_rcpf(x)
#else
#define RCP(x) (1.0f / (x))
#endif

__device__ __forceinline__ unsigned short f2bf(float f) {
  unsigned int u = __builtin_bit_cast(unsigned int, f);
  u += 0x7fffu + ((u >> 16) & 1u);        // round-to-nearest-even
  return (unsigned short)(u >> 16);
}

__device__ __forceinline__ float sigm(float x) {
  return RCP(1.0f + EXP2(-LOG2E * x));
}
__device__ __forceinline__ float tanh_f(float x) {
  return 1.0f - 2.0f * RCP(1.0f + EXP2(2.0f * LOG2E * x));
}

// ---------------------------------------------------------------------------
// Scan kernel: one block = 16 batch rows, full T timesteps of one layer.
// 512 threads = 8 waves. Wave w owns gate columns [w*16, w*16+16) of each of
// the 4 gate blocks (i,f,g,o) -> elementwise stays in-register.
// A_cat LDS = [x_t | h_{t-1}] double-buffered; gates = A_cat @ [W_ih;W_hh]^T.
// ---------------------------------------------------------------------------
template <int KIN, bool IN_BF16>
__global__ __launch_bounds__(512, 2) void lstm_scan(
    const void* __restrict__ in_,            // [B,T,KIN] f32 (L0) or bf16 (L1)
    const float* __restrict__ h0,            // [B,H] layer slice
    const float* __restrict__ c0,            // [B,H] layer slice
    const float* __restrict__ Wih,           // [4H,KIN] f32
    const float* __restrict__ Whh,           // [4H,H]   f32
    const float* __restrict__ bih,           // [4H]
    const float* __restrict__ bhh,           // [4H]
    unsigned short* __restrict__ hout,       // bf16 [B,T,H]
    float* __restrict__ hN,                  // [B,H] slice of d_out
    float* __restrict__ cN)                  // [B,H] slice of d_out
{
  constexpr int AK   = KIN + H;              // concat K: 192 or 256
  constexpr int KC   = AK / 32;              // MFMA K-chunks: 6 or 8
  constexpr int APAD = AK + 8;               // row stride (elems): 400B / 528B rows
  __shared__ __align__(16) unsigned short A[2][16][APAD];

  const int tid   = threadIdx.x;
  const int w     = tid >> 6;                // wave 0..7
  const int l     = tid & 63;
  const int l15   = l & 15;
  const int lhi   = l >> 4;                  // 0..3
  const int jcol  = w * 16 + l15;            // hidden col 0..127
  const int bbase = blockIdx.x * 16;

  // ---- preload weight fragments (B-operand, bf16, stays in VGPRs) ----
  short8 wf[4][KC];
#pragma unroll
  for (int gb = 0; gb < 4; ++gb) {
    const int gc = gb * H + jcol;            // gate row in W
    const float* wi = Wih + (size_t)gc * KIN;
    const float* wh = Whh + (size_t)gc * H;
#pragma unroll
    for (int kc = 0; kc < KC; ++kc) {
      const int k0 = kc * 32 + lhi * 8;
      const float* s = (k0 < KIN) ? (wi + k0) : (wh + (k0 - KIN));
      float4 a = *(const float4*)s;
      float4 b = *(const float4*)(s + 4);
      short8 v;
      v[0] = (short)f2bf(a.x); v[1] = (short)f2bf(a.y);
      v[2] = (short)f2bf(a.z); v[3] = (short)f2bf(a.w);
      v[4] = (short)f2bf(b.x); v[5] = (short)f2bf(b.y);
      v[6] = (short)f2bf(b.z); v[7] = (short)f2bf(b.w);
      wf[gb][kc] = v;
    }
  }

  float bias[4];
#pragma unroll
  for (int gb = 0; gb < 4; ++gb) bias[gb] = bih[gb * H + jcol] + bhh[gb * H + jcol];

  float cst[4], hlast[4];
#pragma unroll
  for (int r = 0; r < 4; ++r)
    cst[r] = c0[(size_t)(bbase + lhi * 4 + r) * H + jcol];

  const float*          inf = (const float*)in_;
  const unsigned short* inb = (const unsigned short*)in_;

  // ---- prologue: stage input(t=0) and h0 into A[0] ----
  if constexpr (!IN_BF16) {
    const int idx = tid * 2, row = idx / KIN, col = idx % KIN;
    float2 v = *(const float2*)(inf + (size_t)(bbase + row) * T * KIN + col);
    unsigned int p = (unsigned int)f2bf(v.x) | ((unsigned int)f2bf(v.y) << 16);
    *(unsigned int*)&A[0][row][col] = p;
  } else {
    const int idx = tid * 4, row = idx / KIN, col = idx % KIN;
    uint2 v = *(const uint2*)(inb + (size_t)(bbase + row) * T * KIN + col);
    *(uint2*)&A[0][row][col] = v;
  }
  {
    const int idx = tid * 4, row = idx / H, col = idx % H;
    float4 v = *(const float4*)(h0 + (size_t)(bbase + row) * H + col);
    uint2 p;
    p.x = (unsigned int)f2bf(v.x) | ((unsigned int)f2bf(v.y) << 16);
    p.y = (unsigned int)f2bf(v.z) | ((unsigned int)f2bf(v.w) << 16);
    *(uint2*)&A[0][row][KIN + col] = p;
  }
  __syncthreads();

  int cur = 0;
  for (int t = 0; t < T; ++t) {
    const int tp = (t + 1 < T) ? (t + 1) : (T - 1);

    // prefetch next input into VGPRs (consumed after the barrier-free MFMA phase)
    float2 pfx; uint2 pfb; int srow, scol;
    if constexpr (!IN_BF16) {
      const int idx = tid * 2; srow = idx / KIN; scol = idx % KIN;
      pfx = *(const float2*)(inf + (size_t)(bbase + srow) * T * KIN + (size_t)tp * KIN + scol);
    } else {
      const int idx = tid * 4; srow = idx / KIN; scol = idx % KIN;
      pfb = *(const uint2*)(inb + (size_t)(bbase + srow) * T * KIN + (size_t)tp * KIN + scol);
    }

    // A-fragments (shared across this wave's 4 gate tiles)
    short8 af[KC];
#pragma unroll
    for (int kc = 0; kc < KC; ++kc)
      af[kc] = *(const short8*)&A[cur][l15][kc * 32 + lhi * 8];

    f32x4 acc[4];
#pragma unroll
    for (int gb = 0; gb < 4; ++gb) {
      f32x4 a = {0.f, 0.f, 0.f, 0.f};
#pragma unroll
      for (int kc = 0; kc < KC; ++kc)
        a = __builtin_amdgcn_mfma_f32_16x16x32_bf16(af[kc], wf[gb][kc], a, 0, 0, 0);
      acc[gb] = a;
    }

    const int nxt = cur ^ 1;
    // stage prefetched input for t+1
    if constexpr (!IN_BF16) {
      unsigned int p = (unsigned int)f2bf(pfx.x) | ((unsigned int)f2bf(pfx.y) << 16);
      *(unsigned int*)&A[nxt][srow][scol] = p;
    } else {
      *(uint2*)&A[nxt][srow][scol] = pfb;
    }

    // elementwise: gates -> c,h ; write h to A[nxt] h-slot + global out buffer
#pragma unroll
    for (int r = 0; r < 4; ++r) {
      const int brow = lhi * 4 + r;
      float i_ = sigm(acc[0][r] + bias[0]);
      float f_ = sigm(acc[1][r] + bias[1]);
      float g_ = tanh_f(acc[2][r] + bias[2]);
      float o_ = sigm(acc[3][r] + bias[3]);
      float c_ = f_ * cst[r] + i_ * g_;
      cst[r] = c_;
      float hn = o_ * tanh_f(c_);
      hlast[r] = hn;
      unsigned short hb = f2bf(hn);
      A[nxt][brow][KIN + jcol] = hb;
      hout[(size_t)(bbase + brow) * T * H + (size_t)t * H + jcol] = hb;
    }
    __syncthreads();
    cur = nxt;
  }

#pragma unroll
  for (int r = 0; r < 4; ++r) {
    const size_t b = bbase + lhi * 4 + r;
    hN[b * H + jcol] = hlast[r];
    cN[b * H + jcol] = cst[r];
  }
}

// ---------------------------------------------------------------------------
// FC: out[BT,32] = out1[BT,128](bf16) @ fc_w^T + fc_b.  64 rows/block, MFMA.
// ---------------------------------------------------------------------------
__global__ __launch_bounds__(256) void fc_kernel(
    const unsigned short* __restrict__ h,    // bf16 [B*T, H]
    const float* __restrict__ Wfc,           // [32,128]
    const float* __restrict__ bfc,           // [32]
    float* __restrict__ out)                 // [B*T, 32]
{
  __shared__ __align__(16) unsigned short a[64][136];
  const int tid = threadIdx.x, w = tid >> 6, l = tid & 63;
  const int l15 = l & 15, lhi = l >> 4;
  const size_t rbase = (size_t)blockIdx.x * 64;

  for (int i = tid; i < 1024; i += 256) {
    const int row = i >> 4, col = (i & 15) * 8;
    *(uint4*)&a[row][col] = *(const uint4*)(h + (rbase + row) * H + col);
  }

  short8 bfr[2][4];
#pragma unroll
  for (int tile = 0; tile < 2; ++tile) {
    const int oc = tile * 16 + l15;
#pragma unroll
    for (int kc = 0; kc < 4; ++kc) {
      const float* s = Wfc + (size_t)oc * H + kc * 32 + lhi * 8;
      float4 x0 = *(const float4*)s;
      float4 x1 = *(const float4*)(s + 4);
      short8 v;
      v[0] = (short)f2bf(x0.x); v[1] = (short)f2bf(x0.y);
      v[2] = (short)f2bf(x0.z); v[3] = (short)f2bf(x0.w);
      v[4] = (short)f2bf(x1.x); v[5] = (short)f2bf(x1.y);
      v[6] = (short)f2bf(x1.z); v[7] = (short)f2bf(x1.w);
      bfr[tile][kc] = v;
    }
  }
  const float bias0 = bfc[l15], bias1 = bfc[16 + l15];
  __syncthreads();

  const int wrow = w * 16;
  short8 af[4];
#pragma unroll
  for (int kc = 0; kc < 4; ++kc)
    af[kc] = *(const short8*)&a[wrow + l15][kc * 32 + lhi * 8];

  f32x4 s0 = {0.f, 0.f, 0.f, 0.f}, s1 = {0.f, 0.f, 0.f, 0.f};
#pragma unroll
  for (int kc = 0; kc < 4; ++kc) {
    s0 = __builtin_amdgcn_mfma_f32_16x16x32_bf16(af[kc], bfr[0][kc], s0, 0, 0, 0);
    s1 = __builtin_amdgcn_mfma_f32_16x16x32_bf16(af[kc], bfr[1][kc], s1, 0, 0, 0);
  }
#pragma unroll
  for (int r = 0; r < 4; ++r) {
    const size_t row = rbase + wrow + lhi * 4 + r;
    out[row * O + l15]      = s0[r] + bias0;
    out[row * O + 16 + l15] = s1[r] + bias1;
  }
}

// ---------------------------------------------------------------------------
extern "C" void kernel_launch(void* const* d_in, const int* in_sizes, int n_in,
                              void* d_out, int out_size, void* d_ws, size_t ws_size,
                              hipStream_t stream) {
  (void)in_sizes; (void)n_in; (void)out_size; (void)ws_size;

  const float* x    = (const float*)d_in[0];
  const float* h0   = (const float*)d_in[1];
  const float* c0   = (const float*)d_in[2];
  const float* Wih0 = (const float*)d_in[3];
  const float* Whh0 = (const float*)d_in[4];
  const float* bih0 = (const float*)d_in[5];
  const float* bhh0 = (const float*)d_in[6];
  const float* Wih1 = (const float*)d_in[7];
  const float* Whh1 = (const float*)d_in[8];
  const float* bih1 = (const float*)d_in[9];
  const float* bhh1 = (const float*)d_in[10];
  const float* fcw  = (const float*)d_in[11];
  const float* fcb  = (const float*)d_in[12];

  unsigned short* out0 = (unsigned short*)d_ws;            // bf16 [B,T,H]
  unsigned short* out1 = out0 + (size_t)B * T * H;         // bf16 [B,T,H]

  float* out = (float*)d_out;                              // [B,T,32]
  float* hN  = out + (size_t)B * T * O;                    // [2,B,H]
  float* cN  = hN + (size_t)2 * B * H;                     // [2,B,H]

  lstm_scan<64, false><<<16, 512, 0, stream>>>(
      x, h0, c0, Wih0, Whh0, bih0, bhh0, out0, hN, cN);
  lstm_scan<128, true><<<16, 512, 0, stream>>>(
      out0, h0 + B * H, c0 + B * H, Wih1, Whh1, bih1, bhh1,
      out1, hN + B * H, cN + B * H);
  fc_kernel<<<(B * T) / 64, 256, 0, stream>>>(out1, fcw, fcb, out);
}

// Round 2
// 1324.412 us; speedup vs baseline: 1.6738x; 1.6738x over previous
//
#include <hip/hip_runtime.h>

// ---------------------------------------------------------------------------
// 2-layer LSTM (B=256,T=1024,in=64,H=128) + fused FC(128->32), bf16 MFMA.
// Layer-pipelined: 32 blocks = 16 L0-blocks + 16 L1-blocks running
// CONCURRENTLY; L1 lags L0 by 2 chunks (CH=16 steps), handoff via global
// out0 + agent-scope release/acquire flags in d_ws.
// ---------------------------------------------------------------------------

static constexpr int B   = 256;
static constexpr int T   = 1024;
static constexpr int H   = 128;
static constexpr int O   = 32;
static constexpr int CH  = 16;        // steps per pipeline chunk
static constexpr int NCH = T / CH;

typedef __attribute__((ext_vector_type(8))) short  short8;
typedef __attribute__((ext_vector_type(4))) float  f32x4;

#define LOG2E 1.4426950408889634f

#if __has_builtin(__builtin_amdgcn_exp2f)
#define EXP2(x) __builtin_amdgcn_exp2f(x)
#else
#define EXP2(x) __expf((x) * 0.69314718056f)
#endif
#if __has_builtin(__builtin_amdgcn_rcpf)
#define RCP(x) __builtin_amdgcn_rcpf(x)
#else
#define RCP(x) (1.0f / (x))
#endif

__device__ __forceinline__ unsigned short f2bf(float f) {
  unsigned int u = __builtin_bit_cast(unsigned int, f);
  u += 0x7fffu + ((u >> 16) & 1u);        // round-to-nearest-even
  return (unsigned short)(u >> 16);
}

__device__ __forceinline__ float sigm(float x) {
  return RCP(1.0f + EXP2(-LOG2E * x));
}
__device__ __forceinline__ float tanh_f(float x) {
  return 1.0f - 2.0f * RCP(1.0f + EXP2(2.0f * LOG2E * x));
}

// ---------------------------------------------------------------------------
// One layer's full-T scan for 16 batch rows. 8 waves; wave w owns gate cols
// [w*16,w*16+16) of each gate block (i,f,g,o) -> elementwise in-register.
// PROD: signal flag after each CH steps. CONS: wait for flag>=k+2 per chunk.
// FUSE_FC (L1): waves 0,1 compute out[.,t-1,.] from h(t-1) frags each step.
// ---------------------------------------------------------------------------
template <int KIN, bool IN_BF16, bool WRITE_HOUT, bool FUSE_FC, bool PROD, bool CONS>
__device__ __forceinline__ void scan_body(
    unsigned short* __restrict__ Ash,
    const void* __restrict__ in_,            // [B,T,KIN] f32 (L0) / bf16 (L1)
    const float* __restrict__ h0,            // [B,H] layer slice
    const float* __restrict__ c0,            // [B,H] layer slice
    const float* __restrict__ Wih,           // [4H,KIN]
    const float* __restrict__ Whh,           // [4H,H]
    const float* __restrict__ bih,           // [4H]
    const float* __restrict__ bhh,           // [4H]
    unsigned short* __restrict__ hout,       // bf16 [B,T,H] (L0 only)
    float* __restrict__ hN,                  // [B,H]
    float* __restrict__ cN,                  // [B,H]
    const float* __restrict__ Wfc,           // [32,128] (L1 only)
    const float* __restrict__ bfc,           // [32]
    float* __restrict__ fco,                 // [B,T,32]
    int* __restrict__ flag, const int bbase)
{
  constexpr int AK   = KIN + H;              // 192 or 256
  constexpr int KC   = AK / 32;              // 6 or 8
  constexpr int APAD = AK + 8;

  const int tid  = threadIdx.x;
  const int w    = tid >> 6;
  const int l    = tid & 63;
  const int l15  = l & 15;
  const int lhi  = l >> 4;
  const int jcol = w * 16 + l15;

#define AEL(buf, row, col) Ash[(((buf) * 16 + (row)) * APAD) + (col)]

  // ---- gate-weight fragments (bf16 B-operand, live in registers) ----
  short8 wf[4][KC];
#pragma unroll
  for (int gb = 0; gb < 4; ++gb) {
    const int gc = gb * H + jcol;
    const float* wi = Wih + (size_t)gc * KIN;
    const float* wh = Whh + (size_t)gc * H;
#pragma unroll
    for (int kc = 0; kc < KC; ++kc) {
      const int k0 = kc * 32 + lhi * 8;
      const float* s = (k0 < KIN) ? (wi + k0) : (wh + (k0 - KIN));
      float4 a = *(const float4*)s;
      float4 b = *(const float4*)(s + 4);
      short8 v;
      v[0] = (short)f2bf(a.x); v[1] = (short)f2bf(a.y);
      v[2] = (short)f2bf(a.z); v[3] = (short)f2bf(a.w);
      v[4] = (short)f2bf(b.x); v[5] = (short)f2bf(b.y);
      v[6] = (short)f2bf(b.z); v[7] = (short)f2bf(b.w);
      wf[gb][kc] = v;
    }
  }
  float bias[4];
#pragma unroll
  for (int gb = 0; gb < 4; ++gb) bias[gb] = bih[gb * H + jcol] + bhh[gb * H + jcol];

  // ---- FC weight fragments (waves 0,1 use them; loads clamped valid) ----
  short8 bfr[4];
  float fcbias = 0.f;
  if constexpr (FUSE_FC) {
    const int oc = (w & 1) * 16 + l15;
#pragma unroll
    for (int kc = 0; kc < 4; ++kc) {
      const float* s = Wfc + (size_t)oc * H + kc * 32 + lhi * 8;
      float4 a = *(const float4*)s;
      float4 b = *(const float4*)(s + 4);
      short8 v;
      v[0] = (short)f2bf(a.x); v[1] = (short)f2bf(a.y);
      v[2] = (short)f2bf(a.z); v[3] = (short)f2bf(a.w);
      v[4] = (short)f2bf(b.x); v[5] = (short)f2bf(b.y);
      v[6] = (short)f2bf(b.z); v[7] = (short)f2bf(b.w);
      bfr[kc] = v;
    }
    fcbias = bfc[oc];
  }

  float cst[4], hlast[4];
#pragma unroll
  for (int r = 0; r < 4; ++r)
    cst[r] = c0[(size_t)(bbase + lhi * 4 + r) * H + jcol];

  const float*          inf = (const float*)in_;
  const unsigned short* inb = (const unsigned short*)in_;

  // ---- consumer: wait for chunks 0,1 before touching in_ ----
  if constexpr (CONS) {
    if (tid == 0) {
      while (__hip_atomic_load(flag, __ATOMIC_ACQUIRE, __HIP_MEMORY_SCOPE_AGENT) < 2)
        __builtin_amdgcn_s_sleep(4);
    }
    __syncthreads();
  }

  // ---- prologue: stage in_(0) and h0 into A[0] ----
  if constexpr (!IN_BF16) {
    const int idx = tid * 2, row = idx / KIN, col = idx % KIN;
    float2 v = *(const float2*)(inf + (size_t)(bbase + row) * T * KIN + col);
    unsigned int p = (unsigned int)f2bf(v.x) | ((unsigned int)f2bf(v.y) << 16);
    *(unsigned int*)&AEL(0, row, col) = p;
  } else {
    const int idx = tid * 4, row = idx / KIN, col = idx % KIN;
    uint2 v = *(const uint2*)(inb + (size_t)(bbase + row) * T * KIN + col);
    *(uint2*)&AEL(0, row, col) = v;
  }
  {
    const int idx = tid * 4, row = idx / H, col = idx % H;
    float4 v = *(const float4*)(h0 + (size_t)(bbase + row) * H + col);
    uint2 p;
    p.x = (unsigned int)f2bf(v.x) | ((unsigned int)f2bf(v.y) << 16);
    p.y = (unsigned int)f2bf(v.z) | ((unsigned int)f2bf(v.w) << 16);
    *(uint2*)&AEL(0, row, KIN + col) = p;
  }
  __syncthreads();

  int cur = 0;
  for (int k = 0; k < NCH; ++k) {
    if constexpr (CONS) {
      if (k > 0) {
        const int want = (k + 2 > NCH) ? NCH : (k + 2);
        if (tid == 0) {
          while (__hip_atomic_load(flag, __ATOMIC_ACQUIRE, __HIP_MEMORY_SCOPE_AGENT) < want)
            __builtin_amdgcn_s_sleep(4);
        }
        __syncthreads();
      }
    }

    for (int tt = 0; tt < CH; ++tt) {
      const int t  = k * CH + tt;
      const int tp = (t + 1 < T) ? (t + 1) : (T - 1);

      // prefetch next input into VGPRs
      float2 pfx; uint2 pfb; int srow, scol;
      if constexpr (!IN_BF16) {
        const int idx = tid * 2; srow = idx / KIN; scol = idx % KIN;
        pfx = *(const float2*)(inf + (size_t)(bbase + srow) * T * KIN + (size_t)tp * KIN + scol);
      } else {
        const int idx = tid * 4; srow = idx / KIN; scol = idx % KIN;
        pfb = *(const uint2*)(inb + (size_t)(bbase + srow) * T * KIN + (size_t)tp * KIN + scol);
      }

      // A-fragments (shared across this wave's 4 gate tiles + FC)
      short8 af[KC];
#pragma unroll
      for (int kc = 0; kc < KC; ++kc)
        af[kc] = *(const short8*)&AEL(cur, l15, kc * 32 + lhi * 8);

      f32x4 acc[4];
#pragma unroll
      for (int gb = 0; gb < 4; ++gb) {
        f32x4 a = {0.f, 0.f, 0.f, 0.f};
#pragma unroll
        for (int kc = 0; kc < KC; ++kc)
          a = __builtin_amdgcn_mfma_f32_16x16x32_bf16(af[kc], wf[gb][kc], a, 0, 0, 0);
        acc[gb] = a;
      }

      // fused FC for step t-1: h(t-1) frags are af[KC-4..KC-1] (cols 128..255)
      f32x4 fs = {0.f, 0.f, 0.f, 0.f};
      if constexpr (FUSE_FC) {
        if (w < 2 && t > 0) {
#pragma unroll
          for (int kc = 0; kc < 4; ++kc)
            fs = __builtin_amdgcn_mfma_f32_16x16x32_bf16(af[KC - 4 + kc], bfr[kc], fs, 0, 0, 0);
        }
      }

      const int nxt = cur ^ 1;
      // stage prefetched input for t+1
      if constexpr (!IN_BF16) {
        unsigned int p = (unsigned int)f2bf(pfx.x) | ((unsigned int)f2bf(pfx.y) << 16);
        *(unsigned int*)&AEL(nxt, srow, scol) = p;
      } else {
        *(uint2*)&AEL(nxt, srow, scol) = pfb;
      }

      // elementwise: gates -> c,h
#pragma unroll
      for (int r = 0; r < 4; ++r) {
        const int brow = lhi * 4 + r;
        float i_ = sigm(acc[0][r] + bias[0]);
        float f_ = sigm(acc[1][r] + bias[1]);
        float g_ = tanh_f(acc[2][r] + bias[2]);
        float o_ = sigm(acc[3][r] + bias[3]);
        float c_ = f_ * cst[r] + i_ * g_;
        cst[r] = c_;
        float hn = o_ * tanh_f(c_);
        hlast[r] = hn;
        unsigned short hb = f2bf(hn);
        AEL(nxt, brow, KIN + jcol) = hb;
        if constexpr (WRITE_HOUT)
          __builtin_nontemporal_store(hb,
              &hout[(size_t)(bbase + brow) * T * H + (size_t)t * H + jcol]);
      }

      if constexpr (FUSE_FC) {
        if (w < 2 && t > 0) {
#pragma unroll
          for (int r = 0; r < 4; ++r)
            fco[((size_t)(bbase + lhi * 4 + r) * T + (t - 1)) * O + (w & 1) * 16 + l15] =
                fs[r] + fcbias;
        }
      }

      __syncthreads();
      cur = nxt;
    }

    if constexpr (PROD) {
      // step-end __syncthreads drained all vmcnt; release flushes L2 for
      // cross-XCD visibility of this chunk's out0 stores.
      if (tid == 0)
        __hip_atomic_store(flag, k + 1, __ATOMIC_RELEASE, __HIP_MEMORY_SCOPE_AGENT);
    }
  }

  // ---- tails ----
#pragma unroll
  for (int r = 0; r < 4; ++r) {
    const size_t b = bbase + lhi * 4 + r;
    hN[b * H + jcol] = hlast[r];
    cN[b * H + jcol] = cst[r];
  }
  if constexpr (FUSE_FC) {
    if (w < 2) {   // FC for final step T-1 from A[cur] h-slot = h(T-1)
      short8 a4[4];
#pragma unroll
      for (int kc = 0; kc < 4; ++kc)
        a4[kc] = *(const short8*)&AEL(cur, l15, KIN + kc * 32 + lhi * 8);
      f32x4 fs = {0.f, 0.f, 0.f, 0.f};
#pragma unroll
      for (int kc = 0; kc < 4; ++kc)
        fs = __builtin_amdgcn_mfma_f32_16x16x32_bf16(a4[kc], bfr[kc], fs, 0, 0, 0);
#pragma unroll
      for (int r = 0; r < 4; ++r)
        fco[((size_t)(bbase + lhi * 4 + r) * T + (T - 1)) * O + (w & 1) * 16 + l15] =
            fs[r] + fcbias;
    }
  }
#undef AEL
}

// ---------------------------------------------------------------------------
__global__ __launch_bounds__(512, 2) void lstm_fused(
    const float* __restrict__ x,
    const float* __restrict__ h0, const float* __restrict__ c0,
    const float* __restrict__ Wih0, const float* __restrict__ Whh0,
    const float* __restrict__ bih0, const float* __restrict__ bhh0,
    const float* __restrict__ Wih1, const float* __restrict__ Whh1,
    const float* __restrict__ bih1, const float* __restrict__ bhh1,
    const float* __restrict__ fcw, const float* __restrict__ fcb,
    unsigned short* __restrict__ out0,
    float* __restrict__ out, float* __restrict__ hN, float* __restrict__ cN,
    int* __restrict__ flags)
{
  __shared__ __align__(16) unsigned short Ash[2 * 16 * 264];
  const int bid = blockIdx.x;
  if (bid < 16) {
    // L0 producer
    scan_body<64, false, true, false, true, false>(
        Ash, x, h0, c0, Wih0, Whh0, bih0, bhh0,
        out0, hN, cN, nullptr, nullptr, nullptr,
        flags + bid, bid * 16);
  } else {
    // L1 consumer + fused FC
    const int rb = bid - 16;
    scan_body<128, true, false, true, false, true>(
        Ash, out0, h0 + B * H, c0 + B * H, Wih1, Whh1, bih1, bhh1,
        nullptr, hN + B * H, cN + B * H, fcw, fcb, out,
        flags + rb, rb * 16);
  }
}

// ---------------------------------------------------------------------------
extern "C" void kernel_launch(void* const* d_in, const int* in_sizes, int n_in,
                              void* d_out, int out_size, void* d_ws, size_t ws_size,
                              hipStream_t stream) {
  (void)in_sizes; (void)n_in; (void)out_size; (void)ws_size;

  const float* x    = (const float*)d_in[0];
  const float* h0   = (const float*)d_in[1];
  const float* c0   = (const float*)d_in[2];
  const float* Wih0 = (const float*)d_in[3];
  const float* Whh0 = (const float*)d_in[4];
  const float* bih0 = (const float*)d_in[5];
  const float* bhh0 = (const float*)d_in[6];
  const float* Wih1 = (const float*)d_in[7];
  const float* Whh1 = (const float*)d_in[8];
  const float* bih1 = (const float*)d_in[9];
  const float* bhh1 = (const float*)d_in[10];
  const float* fcw  = (const float*)d_in[11];
  const float* fcb  = (const float*)d_in[12];

  int*            flags = (int*)d_ws;                          // 16 ints, zeroed
  unsigned short* out0  = (unsigned short*)((char*)d_ws + 1024);  // bf16 [B,T,H]

  float* out = (float*)d_out;                                  // [B,T,32]
  float* hN  = out + (size_t)B * T * O;                        // [2,B,H]
  float* cN  = hN + (size_t)2 * B * H;                         // [2,B,H]

  hipMemsetAsync(d_ws, 0, 1024, stream);   // reset pipeline flags every launch
  lstm_fused<<<32, 512, 0, stream>>>(
      x, h0, c0, Wih0, Whh0, bih0, bhh0, Wih1, Whh1, bih1, bhh1,
      fcw, fcb, out0, out, hN, cN, flags);
}

// Round 3
// 1258.144 us; speedup vs baseline: 1.7620x; 1.0527x over previous
//
#include <hip/hip_runtime.h>

// ---------------------------------------------------------------------------
// 2-layer LSTM (B=256,T=1024,in=64,H=128) + fused FC(128->32), bf16 MFMA.
// Layer-pipelined: 32 blocks = 16 L0 + 16 L1 concurrent; L1 lags L0 by 2
// chunks (CH=16), handoff via global out0 + agent-scope release/acquire.
// R3: per-step raw s_barrier with lgkmcnt-only drain (no vmcnt(0) per step);
// global stores float and are drained once per chunk before the release.
// ---------------------------------------------------------------------------

static constexpr int B   = 256;
static constexpr int T   = 1024;
static constexpr int H   = 128;
static constexpr int O   = 32;
static constexpr int CH  = 16;        // steps per pipeline chunk
static constexpr int NCH = T / CH;

typedef __attribute__((ext_vector_type(8))) short  short8;
typedef __attribute__((ext_vector_type(4))) float  f32x4;

#define LOG2E 1.4426950408889634f

#if __has_builtin(__builtin_amdgcn_exp2f)
#define EXP2(x) __builtin_amdgcn_exp2f(x)
#else
#define EXP2(x) __expf((x) * 0.69314718056f)
#endif
#if __has_builtin(__builtin_amdgcn_rcpf)
#define RCP(x) __builtin_amdgcn_rcpf(x)
#else
#define RCP(x) (1.0f / (x))
#endif

__device__ __forceinline__ unsigned short f2bf(float f) {
  unsigned int u = __builtin_bit_cast(unsigned int, f);
  u += 0x7fffu + ((u >> 16) & 1u);        // round-to-nearest-even
  return (unsigned short)(u >> 16);
}

__device__ __forceinline__ float sigm(float x) {
  return RCP(1.0f + EXP2(-LOG2E * x));
}
__device__ __forceinline__ float tanh_f(float x) {
  return 1.0f - 2.0f * RCP(1.0f + EXP2(2.0f * LOG2E * x));
}

// LDS-only barrier: wait own ds ops, then s_barrier. Global stores float.
__device__ __forceinline__ void block_sync_lds() {
  __builtin_amdgcn_sched_barrier(0);
  asm volatile("s_waitcnt lgkmcnt(0)" ::: "memory");
  __builtin_amdgcn_s_barrier();
  __builtin_amdgcn_sched_barrier(0);
}

// ---------------------------------------------------------------------------
// One layer's full-T scan for 16 batch rows. 8 waves; wave w owns gate cols
// [w*16,w*16+16) of each gate block (i,f,g,o) -> elementwise in-register.
// PROD: drain stores + signal flag after each CH steps. CONS: wait flag>=k+2.
// FUSE_FC (L1): waves 0,1 compute out[.,t-1,.] from h(t-1) frags each step.
// ---------------------------------------------------------------------------
template <int KIN, bool IN_BF16, bool WRITE_HOUT, bool FUSE_FC, bool PROD, bool CONS>
__device__ __forceinline__ void scan_body(
    unsigned short* __restrict__ Ash,
    const void* __restrict__ in_,            // [B,T,KIN] f32 (L0) / bf16 (L1)
    const float* __restrict__ h0,            // [B,H] layer slice
    const float* __restrict__ c0,            // [B,H] layer slice
    const float* __restrict__ Wih,           // [4H,KIN]
    const float* __restrict__ Whh,           // [4H,H]
    const float* __restrict__ bih,           // [4H]
    const float* __restrict__ bhh,           // [4H]
    unsigned short* __restrict__ hout,       // bf16 [B,T,H] (L0 only)
    float* __restrict__ hN,                  // [B,H]
    float* __restrict__ cN,                  // [B,H]
    const float* __restrict__ Wfc,           // [32,128] (L1 only)
    const float* __restrict__ bfc,           // [32]
    float* __restrict__ fco,                 // [B,T,32]
    int* __restrict__ flag, const int bbase)
{
  constexpr int AK   = KIN + H;              // 192 or 256
  constexpr int KC   = AK / 32;              // 6 or 8
  constexpr int APAD = AK + 8;

  const int tid  = threadIdx.x;
  const int w    = tid >> 6;
  const int l    = tid & 63;
  const int l15  = l & 15;
  const int lhi  = l >> 4;
  const int jcol = w * 16 + l15;

#define AEL(buf, row, col) Ash[(((buf) * 16 + (row)) * APAD) + (col)]

  // ---- gate-weight fragments (bf16 B-operand, live in registers) ----
  short8 wf[4][KC];
#pragma unroll
  for (int gb = 0; gb < 4; ++gb) {
    const int gc = gb * H + jcol;
    const float* wi = Wih + (size_t)gc * KIN;
    const float* wh = Whh + (size_t)gc * H;
#pragma unroll
    for (int kc = 0; kc < KC; ++kc) {
      const int k0 = kc * 32 + lhi * 8;
      const float* s = (k0 < KIN) ? (wi + k0) : (wh + (k0 - KIN));
      float4 a = *(const float4*)s;
      float4 b = *(const float4*)(s + 4);
      short8 v;
      v[0] = (short)f2bf(a.x); v[1] = (short)f2bf(a.y);
      v[2] = (short)f2bf(a.z); v[3] = (short)f2bf(a.w);
      v[4] = (short)f2bf(b.x); v[5] = (short)f2bf(b.y);
      v[6] = (short)f2bf(b.z); v[7] = (short)f2bf(b.w);
      wf[gb][kc] = v;
    }
  }
  float bias[4];
#pragma unroll
  for (int gb = 0; gb < 4; ++gb) bias[gb] = bih[gb * H + jcol] + bhh[gb * H + jcol];

  // ---- FC weight fragments (waves 0,1) ----
  short8 bfr[4];
  float fcbias = 0.f;
  if constexpr (FUSE_FC) {
    const int oc = (w & 1) * 16 + l15;
#pragma unroll
    for (int kc = 0; kc < 4; ++kc) {
      const float* s = Wfc + (size_t)oc * H + kc * 32 + lhi * 8;
      float4 a = *(const float4*)s;
      float4 b = *(const float4*)(s + 4);
      short8 v;
      v[0] = (short)f2bf(a.x); v[1] = (short)f2bf(a.y);
      v[2] = (short)f2bf(a.z); v[3] = (short)f2bf(a.w);
      v[4] = (short)f2bf(b.x); v[5] = (short)f2bf(b.y);
      v[6] = (short)f2bf(b.z); v[7] = (short)f2bf(b.w);
      bfr[kc] = v;
    }
    fcbias = bfc[oc];
  }

  float cst[4], hlast[4];
#pragma unroll
  for (int r = 0; r < 4; ++r)
    cst[r] = c0[(size_t)(bbase + lhi * 4 + r) * H + jcol];

  const float*          inf = (const float*)in_;
  const unsigned short* inb = (const unsigned short*)in_;

  // ---- consumer: wait for chunks 0,1 before touching in_ ----
  if constexpr (CONS) {
    if (tid == 0) {
      while (__hip_atomic_load(flag, __ATOMIC_ACQUIRE, __HIP_MEMORY_SCOPE_AGENT) < 2)
        __builtin_amdgcn_s_sleep(4);
    }
    __syncthreads();
  }

  // ---- prologue: stage in_(0) and h0 into A[0] ----
  if constexpr (!IN_BF16) {
    const int idx = tid * 2, row = idx / KIN, col = idx % KIN;
    float2 v = *(const float2*)(inf + (size_t)(bbase + row) * T * KIN + col);
    unsigned int p = (unsigned int)f2bf(v.x) | ((unsigned int)f2bf(v.y) << 16);
    *(unsigned int*)&AEL(0, row, col) = p;
  } else {
    const int idx = tid * 4, row = idx / KIN, col = idx % KIN;
    uint2 v = *(const uint2*)(inb + (size_t)(bbase + row) * T * KIN + col);
    *(uint2*)&AEL(0, row, col) = v;
  }
  {
    const int idx = tid * 4, row = idx / H, col = idx % H;
    float4 v = *(const float4*)(h0 + (size_t)(bbase + row) * H + col);
    uint2 p;
    p.x = (unsigned int)f2bf(v.x) | ((unsigned int)f2bf(v.y) << 16);
    p.y = (unsigned int)f2bf(v.z) | ((unsigned int)f2bf(v.w) << 16);
    *(uint2*)&AEL(0, row, KIN + col) = p;
  }
  __syncthreads();

  int cur = 0;
  for (int k = 0; k < NCH; ++k) {
    if constexpr (CONS) {
      if (k > 0) {
        const int want = (k + 2 > NCH) ? NCH : (k + 2);
        if (tid == 0) {
          while (__hip_atomic_load(flag, __ATOMIC_ACQUIRE, __HIP_MEMORY_SCOPE_AGENT) < want)
            __builtin_amdgcn_s_sleep(4);
        }
        __syncthreads();
      }
    }

    for (int tt = 0; tt < CH; ++tt) {
      const int t  = k * CH + tt;
      const int tp = (t + 1 < T) ? (t + 1) : (T - 1);

      // prefetch next input into VGPRs
      float2 pfx; uint2 pfb; int srow, scol;
      if constexpr (!IN_BF16) {
        const int idx = tid * 2; srow = idx / KIN; scol = idx % KIN;
        pfx = *(const float2*)(inf + (size_t)(bbase + srow) * T * KIN + (size_t)tp * KIN + scol);
      } else {
        const int idx = tid * 4; srow = idx / KIN; scol = idx % KIN;
        pfb = *(const uint2*)(inb + (size_t)(bbase + srow) * T * KIN + (size_t)tp * KIN + scol);
      }

      // A-fragments (shared across this wave's 4 gate tiles + FC)
      short8 af[KC];
#pragma unroll
      for (int kc = 0; kc < KC; ++kc)
        af[kc] = *(const short8*)&AEL(cur, l15, kc * 32 + lhi * 8);

      f32x4 acc[4];
#pragma unroll
      for (int gb = 0; gb < 4; ++gb) {
        f32x4 a = {0.f, 0.f, 0.f, 0.f};
#pragma unroll
        for (int kc = 0; kc < KC; ++kc)
          a = __builtin_amdgcn_mfma_f32_16x16x32_bf16(af[kc], wf[gb][kc], a, 0, 0, 0);
        acc[gb] = a;
      }

      // fused FC for step t-1: h(t-1) frags are af[KC-4..KC-1]
      f32x4 fs = {0.f, 0.f, 0.f, 0.f};
      if constexpr (FUSE_FC) {
        if (w < 2 && t > 0) {
#pragma unroll
          for (int kc = 0; kc < 4; ++kc)
            fs = __builtin_amdgcn_mfma_f32_16x16x32_bf16(af[KC - 4 + kc], bfr[kc], fs, 0, 0, 0);
        }
      }

      const int nxt = cur ^ 1;
      // stage prefetched input for t+1
      if constexpr (!IN_BF16) {
        unsigned int p = (unsigned int)f2bf(pfx.x) | ((unsigned int)f2bf(pfx.y) << 16);
        *(unsigned int*)&AEL(nxt, srow, scol) = p;
      } else {
        *(uint2*)&AEL(nxt, srow, scol) = pfb;
      }

      // elementwise: gates -> c,h
#pragma unroll
      for (int r = 0; r < 4; ++r) {
        const int brow = lhi * 4 + r;
        float i_ = sigm(acc[0][r] + bias[0]);
        float f_ = sigm(acc[1][r] + bias[1]);
        float g_ = tanh_f(acc[2][r] + bias[2]);
        float o_ = sigm(acc[3][r] + bias[3]);
        float c_ = f_ * cst[r] + i_ * g_;
        cst[r] = c_;
        float hn = o_ * tanh_f(c_);
        hlast[r] = hn;
        unsigned short hb = f2bf(hn);
        AEL(nxt, brow, KIN + jcol) = hb;
        if constexpr (WRITE_HOUT)
          hout[(size_t)(bbase + brow) * T * H + (size_t)t * H + jcol] = hb;
      }

      if constexpr (FUSE_FC) {
        if (w < 2 && t > 0) {
#pragma unroll
          for (int r = 0; r < 4; ++r)
            fco[((size_t)(bbase + lhi * 4 + r) * T + (t - 1)) * O + (w & 1) * 16 + l15] =
                fs[r] + fcbias;
        }
      }

      // LDS-only sync: global stores float across steps
      block_sync_lds();
      cur = nxt;
    }

    if constexpr (PROD) {
      // all waves drain own global stores, then barrier, then release:
      // wbl2 from the agent-scope release makes the chunk visible cross-XCD.
      __builtin_amdgcn_sched_barrier(0);
      asm volatile("s_waitcnt vmcnt(0)" ::: "memory");
      __builtin_amdgcn_s_barrier();
      if (tid == 0)
        __hip_atomic_store(flag, k + 1, __ATOMIC_RELEASE, __HIP_MEMORY_SCOPE_AGENT);
    }
  }

  // ---- tails ----
#pragma unroll
  for (int r = 0; r < 4; ++r) {
    const size_t b = bbase + lhi * 4 + r;
    hN[b * H + jcol] = hlast[r];
    cN[b * H + jcol] = cst[r];
  }
  if constexpr (FUSE_FC) {
    if (w < 2) {   // FC for final step T-1 from A[cur] h-slot = h(T-1)
      short8 a4[4];
#pragma unroll
      for (int kc = 0; kc < 4; ++kc)
        a4[kc] = *(const short8*)&AEL(cur, l15, KIN + kc * 32 + lhi * 8);
      f32x4 fs = {0.f, 0.f, 0.f, 0.f};
#pragma unroll
      for (int kc = 0; kc < 4; ++kc)
        fs = __builtin_amdgcn_mfma_f32_16x16x32_bf16(a4[kc], bfr[kc], fs, 0, 0, 0);
#pragma unroll
      for (int r = 0; r < 4; ++r)
        fco[((size_t)(bbase + lhi * 4 + r) * T + (T - 1)) * O + (w & 1) * 16 + l15] =
            fs[r] + fcbias;
    }
  }
#undef AEL
}

// ---------------------------------------------------------------------------
__global__ __launch_bounds__(512, 2) void lstm_fused(
    const float* __restrict__ x,
    const float* __restrict__ h0, const float* __restrict__ c0,
    const float* __restrict__ Wih0, const float* __restrict__ Whh0,
    const float* __restrict__ bih0, const float* __restrict__ bhh0,
    const float* __restrict__ Wih1, const float* __restrict__ Whh1,
    const float* __restrict__ bih1, const float* __restrict__ bhh1,
    const float* __restrict__ fcw, const float* __restrict__ fcb,
    unsigned short* __restrict__ out0,
    float* __restrict__ out, float* __restrict__ hN, float* __restrict__ cN,
    int* __restrict__ flags)
{
  __shared__ __align__(16) unsigned short Ash[2 * 16 * 264];
  const int bid = blockIdx.x;
  if (bid < 16) {
    // L0 producer
    scan_body<64, false, true, false, true, false>(
        Ash, x, h0, c0, Wih0, Whh0, bih0, bhh0,
        out0, hN, cN, nullptr, nullptr, nullptr,
        flags + bid, bid * 16);
  } else {
    // L1 consumer + fused FC
    const int rb = bid - 16;
    scan_body<128, true, false, true, false, true>(
        Ash, out0, h0 + B * H, c0 + B * H, Wih1, Whh1, bih1, bhh1,
        nullptr, hN + B * H, cN + B * H, fcw, fcb, out,
        flags + rb, rb * 16);
  }
}

// ---------------------------------------------------------------------------
extern "C" void kernel_launch(void* const* d_in, const int* in_sizes, int n_in,
                              void* d_out, int out_size, void* d_ws, size_t ws_size,
                              hipStream_t stream) {
  (void)in_sizes; (void)n_in; (void)out_size; (void)ws_size;

  const float* x    = (const float*)d_in[0];
  const float* h0   = (const float*)d_in[1];
  const float* c0   = (const float*)d_in[2];
  const float* Wih0 = (const float*)d_in[3];
  const float* Whh0 = (const float*)d_in[4];
  const float* bih0 = (const float*)d_in[5];
  const float* bhh0 = (const float*)d_in[6];
  const float* Wih1 = (const float*)d_in[7];
  const float* Whh1 = (const float*)d_in[8];
  const float* bih1 = (const float*)d_in[9];
  const float* bhh1 = (const float*)d_in[10];
  const float* fcw  = (const float*)d_in[11];
  const float* fcb  = (const float*)d_in[12];

  int*            flags = (int*)d_ws;                             // 16 ints
  unsigned short* out0  = (unsigned short*)((char*)d_ws + 1024);  // bf16 [B,T,H]

  float* out = (float*)d_out;                                     // [B,T,32]
  float* hN  = out + (size_t)B * T * O;                           // [2,B,H]
  float* cN  = hN + (size_t)2 * B * H;                            // [2,B,H]

  hipMemsetAsync(d_ws, 0, 1024, stream);   // reset pipeline flags every launch
  lstm_fused<<<32, 512, 0, stream>>>(
      x, h0, c0, Wih0, Whh0, bih0, bhh0, Wih1, Whh1, bih1, bhh1,
      fcw, fcb, out0, out, hN, cN, flags);
}

// Round 4
// 1228.014 us; speedup vs baseline: 1.8052x; 1.0245x over previous
//
#include <hip/hip_runtime.h>

// ---------------------------------------------------------------------------
// 2-layer LSTM (B=256,T=1024,in=64,H=128) + fused FC(128->32), bf16 MFMA.
// Layer-pipelined: 32 blocks = 16 L0 + 16 L1 concurrent; L1 lags L0 by 2
// chunks (CH=16), handoff via global out0 + agent-scope release/acquire.
// R4: 2-step-deep register prefetch of the input stream (kills per-step
// global-load-latency stall on the vmcnt FIFO); bias folded into MFMA acc
// init; strength-reduced store/load addressing.
// ---------------------------------------------------------------------------

static constexpr int B   = 256;
static constexpr int T   = 1024;
static constexpr int H   = 128;
static constexpr int O   = 32;
static constexpr int CH  = 16;        // steps per pipeline chunk
static constexpr int NCH = T / CH;

typedef __attribute__((ext_vector_type(8))) short  short8;
typedef __attribute__((ext_vector_type(4))) float  f32x4;

#define LOG2E 1.4426950408889634f

#if __has_builtin(__builtin_amdgcn_exp2f)
#define EXP2(x) __builtin_amdgcn_exp2f(x)
#else
#define EXP2(x) __expf((x) * 0.69314718056f)
#endif
#if __has_builtin(__builtin_amdgcn_rcpf)
#define RCP(x) __builtin_amdgcn_rcpf(x)
#else
#define RCP(x) (1.0f / (x))
#endif

__device__ __forceinline__ unsigned short f2bf(float f) {
  unsigned int u = __builtin_bit_cast(unsigned int, f);
  u += 0x7fffu + ((u >> 16) & 1u);        // round-to-nearest-even
  return (unsigned short)(u >> 16);
}

__device__ __forceinline__ float sigm(float x) {
  return RCP(1.0f + EXP2(-LOG2E * x));
}
__device__ __forceinline__ float tanh_f(float x) {
  return 1.0f - 2.0f * RCP(1.0f + EXP2(2.0f * LOG2E * x));
}

// LDS-only barrier: wait own ds ops, then s_barrier. Global ops float.
__device__ __forceinline__ void block_sync_lds() {
  __builtin_amdgcn_sched_barrier(0);
  asm volatile("s_waitcnt lgkmcnt(0)" ::: "memory");
  __builtin_amdgcn_s_barrier();
  __builtin_amdgcn_sched_barrier(0);
}

// ---------------------------------------------------------------------------
// One layer's full-T scan for 16 batch rows. 8 waves; wave w owns gate cols
// [w*16,w*16+16) of each gate block (i,f,g,o) -> elementwise in-register.
// PROD: drain stores + signal flag after each CH steps. CONS: wait flag>=k+2.
// FUSE_FC (L1): waves 0,1 compute out[.,t-1,.] from h(t-1) frags each step.
// ---------------------------------------------------------------------------
template <int KIN, bool IN_BF16, bool WRITE_HOUT, bool FUSE_FC, bool PROD, bool CONS>
__device__ __forceinline__ void scan_body(
    unsigned short* __restrict__ Ash,
    const void* __restrict__ in_,            // [B,T,KIN] f32 (L0) / bf16 (L1)
    const float* __restrict__ h0,            // [B,H] layer slice
    const float* __restrict__ c0,            // [B,H] layer slice
    const float* __restrict__ Wih,           // [4H,KIN]
    const float* __restrict__ Whh,           // [4H,H]
    const float* __restrict__ bih,           // [4H]
    const float* __restrict__ bhh,           // [4H]
    unsigned short* __restrict__ hout,       // bf16 [B,T,H] (L0 only)
    float* __restrict__ hN,                  // [B,H]
    float* __restrict__ cN,                  // [B,H]
    const float* __restrict__ Wfc,           // [32,128] (L1 only)
    const float* __restrict__ bfc,           // [32]
    float* __restrict__ fco,                 // [B,T,32]
    int* __restrict__ flag, const int bbase)
{
  constexpr int AK   = KIN + H;              // 192 or 256
  constexpr int KC   = AK / 32;              // 6 or 8
  constexpr int APAD = AK + 8;

  const int tid  = threadIdx.x;
  const int w    = tid >> 6;
  const int l    = tid & 63;
  const int l15  = l & 15;
  const int lhi  = l >> 4;
  const int jcol = w * 16 + l15;

#define AEL(buf, row, col) Ash[(((buf) * 16 + (row)) * APAD) + (col)]

  // ---- gate-weight fragments (bf16 B-operand, live in registers) ----
  short8 wf[4][KC];
#pragma unroll
  for (int gb = 0; gb < 4; ++gb) {
    const int gc = gb * H + jcol;
    const float* wi = Wih + (size_t)gc * KIN;
    const float* wh = Whh + (size_t)gc * H;
#pragma unroll
    for (int kc = 0; kc < KC; ++kc) {
      const int k0 = kc * 32 + lhi * 8;
      const float* s = (k0 < KIN) ? (wi + k0) : (wh + (k0 - KIN));
      float4 a = *(const float4*)s;
      float4 b = *(const float4*)(s + 4);
      short8 v;
      v[0] = (short)f2bf(a.x); v[1] = (short)f2bf(a.y);
      v[2] = (short)f2bf(a.z); v[3] = (short)f2bf(a.w);
      v[4] = (short)f2bf(b.x); v[5] = (short)f2bf(b.y);
      v[6] = (short)f2bf(b.z); v[7] = (short)f2bf(b.w);
      wf[gb][kc] = v;
    }
  }
  float bias[4];
#pragma unroll
  for (int gb = 0; gb < 4; ++gb) bias[gb] = bih[gb * H + jcol] + bhh[gb * H + jcol];

  // ---- FC weight fragments (waves 0,1) ----
  short8 bfr[4];
  float fcbias = 0.f;
  if constexpr (FUSE_FC) {
    const int oc = (w & 1) * 16 + l15;
#pragma unroll
    for (int kc = 0; kc < 4; ++kc) {
      const float* s = Wfc + (size_t)oc * H + kc * 32 + lhi * 8;
      float4 a = *(const float4*)s;
      float4 b = *(const float4*)(s + 4);
      short8 v;
      v[0] = (short)f2bf(a.x); v[1] = (short)f2bf(a.y);
      v[2] = (short)f2bf(a.z); v[3] = (short)f2bf(a.w);
      v[4] = (short)f2bf(b.x); v[5] = (short)f2bf(b.y);
      v[6] = (short)f2bf(b.z); v[7] = (short)f2bf(b.w);
      bfr[kc] = v;
    }
    fcbias = bfc[oc];
  }

  float cst[4], hlast[4];
#pragma unroll
  for (int r = 0; r < 4; ++r)
    cst[r] = c0[(size_t)(bbase + lhi * 4 + r) * H + jcol];

  const float*          inf = (const float*)in_;
  const unsigned short* inb = (const unsigned short*)in_;

  // lane-constant input coordinates + running lane pointers
  int srow, scol;
  if constexpr (!IN_BF16) { srow = (tid * 2) / KIN; scol = (tid * 2) % KIN; }
  else                    { srow = (tid * 4) / KIN; scol = (tid * 4) % KIN; }
  const float*          xpf = inf + (size_t)(bbase + srow) * T * KIN + scol;
  const unsigned short* xpb = inb + (size_t)(bbase + srow) * T * KIN + scol;

  unsigned short* hp = nullptr;
  if constexpr (WRITE_HOUT)
    hp = hout + (size_t)(bbase + lhi * 4) * T * H + jcol;   // r stride = T*H
  float* fp = nullptr;
  if constexpr (FUSE_FC)
    fp = fco + (size_t)(bbase + lhi * 4) * T * O + (w & 1) * 16 + l15;

  // ---- consumer: wait for chunks 0,1 before touching in_ ----
  if constexpr (CONS) {
    if (tid == 0) {
      while (__hip_atomic_load(flag, __ATOMIC_ACQUIRE, __HIP_MEMORY_SCOPE_AGENT) < 2)
        __builtin_amdgcn_s_sleep(4);
    }
    __syncthreads();
  }

  // ---- prologue: stage in_(0) and h0 into A[0]; preload in_(1) ----
  if constexpr (!IN_BF16) {
    float2 v = *(const float2*)xpf;
    unsigned int p = (unsigned int)f2bf(v.x) | ((unsigned int)f2bf(v.y) << 16);
    *(unsigned int*)&AEL(0, srow, scol) = p;
  } else {
    uint2 v = *(const uint2*)xpb;
    *(uint2*)&AEL(0, srow, scol) = v;
  }
  {
    const int idx = tid * 4, row = idx / H, col = idx % H;
    float4 v = *(const float4*)(h0 + (size_t)(bbase + row) * H + col);
    uint2 p;
    p.x = (unsigned int)f2bf(v.x) | ((unsigned int)f2bf(v.y) << 16);
    p.y = (unsigned int)f2bf(v.z) | ((unsigned int)f2bf(v.w) << 16);
    *(uint2*)&AEL(0, row, KIN + col) = p;
  }

  float2 pfoF; uint2 pfoB;                    // pf_old = x(t+1)
  if constexpr (!IN_BF16) pfoF = *(const float2*)(xpf + KIN);
  else                    pfoB = *(const uint2*)(xpb + KIN);
  xpf += 2 * (size_t)KIN;                     // points at x(t+2)
  xpb += 2 * (size_t)KIN;
  __syncthreads();

  int cur = 0;
  for (int k = 0; k < NCH; ++k) {
    if constexpr (CONS) {
      if (k > 0) {
        const int want = (k + 2 > NCH) ? NCH : (k + 2);
        if (tid == 0) {
          while (__hip_atomic_load(flag, __ATOMIC_ACQUIRE, __HIP_MEMORY_SCOPE_AGENT) < want)
            __builtin_amdgcn_s_sleep(4);
        }
        __syncthreads();
      }
    }

    for (int tt = 0; tt < CH; ++tt) {
      const int t   = k * CH + tt;
      const int nxt = cur ^ 1;

      // issue load of x(t+2) (2-step-deep pipeline)
      float2 pfnF; uint2 pfnB;
      if constexpr (!IN_BF16) pfnF = *(const float2*)xpf;
      else                    pfnB = *(const uint2*)xpb;

      // write x(t+1) = pf_old into A[nxt] (vmcnt wait ~0: issued last step)
      if constexpr (!IN_BF16) {
        unsigned int p = (unsigned int)f2bf(pfoF.x) | ((unsigned int)f2bf(pfoF.y) << 16);
        *(unsigned int*)&AEL(nxt, srow, scol) = p;
      } else {
        *(uint2*)&AEL(nxt, srow, scol) = pfnB, // placeholder avoided below
        *(uint2*)&AEL(nxt, srow, scol) = pfoB;
      }

      // A-fragments (shared across this wave's 4 gate tiles + FC)
      short8 af[KC];
#pragma unroll
      for (int kc = 0; kc < KC; ++kc)
        af[kc] = *(const short8*)&AEL(cur, l15, kc * 32 + lhi * 8);

      f32x4 acc[4];
#pragma unroll
      for (int gb = 0; gb < 4; ++gb) {
        f32x4 a = {bias[gb], bias[gb], bias[gb], bias[gb]};
#pragma unroll
        for (int kc = 0; kc < KC; ++kc)
          a = __builtin_amdgcn_mfma_f32_16x16x32_bf16(af[kc], wf[gb][kc], a, 0, 0, 0);
        acc[gb] = a;
      }

      // fused FC for step t-1: h(t-1) frags are af[KC-4..KC-1]
      f32x4 fs = {fcbias, fcbias, fcbias, fcbias};
      if constexpr (FUSE_FC) {
        if (w < 2 && t > 0) {
#pragma unroll
          for (int kc = 0; kc < 4; ++kc)
            fs = __builtin_amdgcn_mfma_f32_16x16x32_bf16(af[KC - 4 + kc], bfr[kc], fs, 0, 0, 0);
        }
      }

      // elementwise: gates -> c,h
#pragma unroll
      for (int r = 0; r < 4; ++r) {
        const int brow = lhi * 4 + r;
        float i_ = sigm(acc[0][r]);
        float f_ = sigm(acc[1][r]);
        float g_ = tanh_f(acc[2][r]);
        float o_ = sigm(acc[3][r]);
        float c_ = f_ * cst[r] + i_ * g_;
        cst[r] = c_;
        float hn = o_ * tanh_f(c_);
        hlast[r] = hn;
        unsigned short hb = f2bf(hn);
        AEL(nxt, brow, KIN + jcol) = hb;
        if constexpr (WRITE_HOUT)
          hp[(size_t)r * (T * H)] = hb;
      }
      if constexpr (WRITE_HOUT) hp += H;

      if constexpr (FUSE_FC) {
        if (w < 2 && t > 0) {
          float* f0 = fp + (size_t)(t - 1) * O;
#pragma unroll
          for (int r = 0; r < 4; ++r)
            f0[(size_t)r * (T * O)] = fs[r];
        }
      }

      // LDS-only sync: global ops float across steps
      block_sync_lds();
      cur = nxt;
      pfoF = pfnF; pfoB = pfnB;
      if (t < T - 3) { xpf += KIN; xpb += KIN; }
    }

    if constexpr (PROD) {
      // drain own global stores, barrier, then agent-scope release.
      __builtin_amdgcn_sched_barrier(0);
      asm volatile("s_waitcnt vmcnt(0)" ::: "memory");
      __builtin_amdgcn_s_barrier();
      if (tid == 0)
        __hip_atomic_store(flag, k + 1, __ATOMIC_RELEASE, __HIP_MEMORY_SCOPE_AGENT);
    }
  }

  // ---- tails ----
#pragma unroll
  for (int r = 0; r < 4; ++r) {
    const size_t b = bbase + lhi * 4 + r;
    hN[b * H + jcol] = hlast[r];
    cN[b * H + jcol] = cst[r];
  }
  if constexpr (FUSE_FC) {
    if (w < 2) {   // FC for final step T-1 from A[cur] h-slot = h(T-1)
      short8 a4[4];
#pragma unroll
      for (int kc = 0; kc < 4; ++kc)
        a4[kc] = *(const short8*)&AEL(cur, l15, KIN + kc * 32 + lhi * 8);
      f32x4 fs = {fcbias, fcbias, fcbias, fcbias};
#pragma unroll
      for (int kc = 0; kc < 4; ++kc)
        fs = __builtin_amdgcn_mfma_f32_16x16x32_bf16(a4[kc], bfr[kc], fs, 0, 0, 0);
      float* f0 = fp + (size_t)(T - 1) * O;
#pragma unroll
      for (int r = 0; r < 4; ++r)
        f0[(size_t)r * (T * O)] = fs[r];
    }
  }
#undef AEL
}

// ---------------------------------------------------------------------------
__global__ __launch_bounds__(512, 2) void lstm_fused(
    const float* __restrict__ x,
    const float* __restrict__ h0, const float* __restrict__ c0,
    const float* __restrict__ Wih0, const float* __restrict__ Whh0,
    const float* __restrict__ bih0, const float* __restrict__ bhh0,
    const float* __restrict__ Wih1, const float* __restrict__ Whh1,
    const float* __restrict__ bih1, const float* __restrict__ bhh1,
    const float* __restrict__ fcw, const float* __restrict__ fcb,
    unsigned short* __restrict__ out0,
    float* __restrict__ out, float* __restrict__ hN, float* __restrict__ cN,
    int* __restrict__ flags)
{
  __shared__ __align__(16) unsigned short Ash[2 * 16 * 264];
  const int bid = blockIdx.x;
  if (bid < 16) {
    // L0 producer
    scan_body<64, false, true, false, true, false>(
        Ash, x, h0, c0, Wih0, Whh0, bih0, bhh0,
        out0, hN, cN, nullptr, nullptr, nullptr,
        flags + bid, bid * 16);
  } else {
    // L1 consumer + fused FC
    const int rb = bid - 16;
    scan_body<128, true, false, true, false, true>(
        Ash, out0, h0 + B * H, c0 + B * H, Wih1, Whh1, bih1, bhh1,
        nullptr, hN + B * H, cN + B * H, fcw, fcb, out,
        flags + rb, rb * 16);
  }
}

// ---------------------------------------------------------------------------
extern "C" void kernel_launch(void* const* d_in, const int* in_sizes, int n_in,
                              void* d_out, int out_size, void* d_ws, size_t ws_size,
                              hipStream_t stream) {
  (void)in_sizes; (void)n_in; (void)out_size; (void)ws_size;

  const float* x    = (const float*)d_in[0];
  const float* h0   = (const float*)d_in[1];
  const float* c0   = (const float*)d_in[2];
  const float* Wih0 = (const float*)d_in[3];
  const float* Whh0 = (const float*)d_in[4];
  const float* bih0 = (const float*)d_in[5];
  const float* bhh0 = (const float*)d_in[6];
  const float* Wih1 = (const float*)d_in[7];
  const float* Whh1 = (const float*)d_in[8];
  const float* bih1 = (const float*)d_in[9];
  const float* bhh1 = (const float*)d_in[10];
  const float* fcw  = (const float*)d_in[11];
  const float* fcb  = (const float*)d_in[12];

  int*            flags = (int*)d_ws;                             // 16 ints
  unsigned short* out0  = (unsigned short*)((char*)d_ws + 1024);  // bf16 [B,T,H]

  float* out = (float*)d_out;                                     // [B,T,32]
  float* hN  = out + (size_t)B * T * O;                           // [2,B,H]
  float* cN  = hN + (size_t)2 * B * H;                            // [2,B,H]

  hipMemsetAsync(d_ws, 0, 1024, stream);   // reset pipeline flags every launch
  lstm_fused<<<32, 512, 0, stream>>>(
      x, h0, c0, Wih0, Whh0, bih0, bhh0, Wih1, Whh1, bih1, bhh1,
      fcw, fcb, out0, out, hN, cN, flags);
}

// Round 5
// 978.518 us; speedup vs baseline: 2.2655x; 1.2550x over previous
//
#include <hip/hip_runtime.h>

// ---------------------------------------------------------------------------
// 2-layer LSTM (B=256,T=1024,in=64,H=128) + fused FC(128->32), bf16 MFMA.
// Layer-pipelined: 64 blocks = 32 L0 + 32 L1 concurrent; L1 lags L0 by 2
// chunks (CH=16), handoff via global out0 + agent-scope release/acquire.
// R5: (a) fix L1 staging bug that re-serialized the prefetch (comma-expr
// stored the just-issued load -> vmcnt(0) stall every step); (b) scale out
// to 8 rows/block with row-interleave mapping b -> (b>>1)*4+(b&1) so each
// lane owns 2 valid C-rows -> elementwise/trans work per lane halves
// uniformly (no divergence).
// ---------------------------------------------------------------------------

static constexpr int B   = 256;
static constexpr int T   = 1024;
static constexpr int H   = 128;
static constexpr int O   = 32;
static constexpr int R   = 8;         // batch rows per block
static constexpr int NBL = B / R;     // 32 blocks per layer
static constexpr int CH  = 16;        // steps per pipeline chunk
static constexpr int NCH = T / CH;

typedef __attribute__((ext_vector_type(8))) short  short8;
typedef __attribute__((ext_vector_type(4))) float  f32x4;

#define LOG2E 1.4426950408889634f

#if __has_builtin(__builtin_amdgcn_exp2f)
#define EXP2(x) __builtin_amdgcn_exp2f(x)
#else
#define EXP2(x) __expf((x) * 0.69314718056f)
#endif
#if __has_builtin(__builtin_amdgcn_rcpf)
#define RCP(x) __builtin_amdgcn_rcpf(x)
#else
#define RCP(x) (1.0f / (x))
#endif

__device__ __forceinline__ unsigned short f2bf(float f) {
  unsigned int u = __builtin_bit_cast(unsigned int, f);
  u += 0x7fffu + ((u >> 16) & 1u);        // round-to-nearest-even
  return (unsigned short)(u >> 16);
}

__device__ __forceinline__ float sigm(float x) {
  return RCP(1.0f + EXP2(-LOG2E * x));
}
__device__ __forceinline__ float tanh_f(float x) {
  return 1.0f - 2.0f * RCP(1.0f + EXP2(2.0f * LOG2E * x));
}

// LDS-only barrier: wait own ds ops, then s_barrier. Global ops float.
__device__ __forceinline__ void block_sync_lds() {
  __builtin_amdgcn_sched_barrier(0);
  asm volatile("s_waitcnt lgkmcnt(0)" ::: "memory");
  __builtin_amdgcn_s_barrier();
  __builtin_amdgcn_sched_barrier(0);
}

// batch row (0..7) -> MFMA/LDS tile row (rows {0,1,4,5,8,9,12,13})
__device__ __forceinline__ int mrow(int b) { return ((b >> 1) << 2) | (b & 1); }

// ---------------------------------------------------------------------------
// One layer's full-T scan for R=8 batch rows. 8 waves; wave w owns gate cols
// [w*16,w*16+16) of each gate block (i,f,g,o) -> elementwise in-register,
// 2 valid C-rows per lane. PROD: drain + flag after each CH steps.
// CONS: wait flag>=k+2. FUSE_FC (L1): waves 0,1 emit out[.,t-1,.] each step.
// ---------------------------------------------------------------------------
template <int KIN, bool IN_BF16, bool WRITE_HOUT, bool FUSE_FC, bool PROD, bool CONS>
__device__ __forceinline__ void scan_body(
    unsigned short* __restrict__ Ash,
    const void* __restrict__ in_,            // [B,T,KIN] f32 (L0) / bf16 (L1)
    const float* __restrict__ h0,            // [B,H] layer slice
    const float* __restrict__ c0,            // [B,H] layer slice
    const float* __restrict__ Wih,           // [4H,KIN]
    const float* __restrict__ Whh,           // [4H,H]
    const float* __restrict__ bih,           // [4H]
    const float* __restrict__ bhh,           // [4H]
    unsigned short* __restrict__ hout,       // bf16 [B,T,H] (L0 only)
    float* __restrict__ hN,                  // [B,H]
    float* __restrict__ cN,                  // [B,H]
    const float* __restrict__ Wfc,           // [32,128] (L1 only)
    const float* __restrict__ bfc,           // [32]
    float* __restrict__ fco,                 // [B,T,32]
    int* __restrict__ flag, const int bbase)
{
  constexpr int AK   = KIN + H;              // 192 or 256
  constexpr int KC   = AK / 32;              // 6 or 8
  constexpr int APAD = AK + 8;

  const int tid  = threadIdx.x;
  const int w    = tid >> 6;
  const int l    = tid & 63;
  const int l15  = l & 15;
  const int lhi  = l >> 4;
  const int jcol = w * 16 + l15;

#define AEL(buf, row, col) Ash[(((buf) * 16 + (row)) * APAD) + (col)]

  // ---- gate-weight fragments (bf16 B-operand, live in registers) ----
  short8 wf[4][KC];
#pragma unroll
  for (int gb = 0; gb < 4; ++gb) {
    const int gc = gb * H + jcol;
    const float* wi = Wih + (size_t)gc * KIN;
    const float* wh = Whh + (size_t)gc * H;
#pragma unroll
    for (int kc = 0; kc < KC; ++kc) {
      const int k0 = kc * 32 + lhi * 8;
      const float* s = (k0 < KIN) ? (wi + k0) : (wh + (k0 - KIN));
      float4 a = *(const float4*)s;
      float4 b = *(const float4*)(s + 4);
      short8 v;
      v[0] = (short)f2bf(a.x); v[1] = (short)f2bf(a.y);
      v[2] = (short)f2bf(a.z); v[3] = (short)f2bf(a.w);
      v[4] = (short)f2bf(b.x); v[5] = (short)f2bf(b.y);
      v[6] = (short)f2bf(b.z); v[7] = (short)f2bf(b.w);
      wf[gb][kc] = v;
    }
  }
  float bias[4];
#pragma unroll
  for (int gb = 0; gb < 4; ++gb) bias[gb] = bih[gb * H + jcol] + bhh[gb * H + jcol];

  // ---- FC weight fragments (waves 0,1) ----
  short8 bfr[4];
  float fcbias = 0.f;
  if constexpr (FUSE_FC) {
    const int oc = (w & 1) * 16 + l15;
#pragma unroll
    for (int kc = 0; kc < 4; ++kc) {
      const float* s = Wfc + (size_t)oc * H + kc * 32 + lhi * 8;
      float4 a = *(const float4*)s;
      float4 b = *(const float4*)(s + 4);
      short8 v;
      v[0] = (short)f2bf(a.x); v[1] = (short)f2bf(a.y);
      v[2] = (short)f2bf(a.z); v[3] = (short)f2bf(a.w);
      v[4] = (short)f2bf(b.x); v[5] = (short)f2bf(b.y);
      v[6] = (short)f2bf(b.z); v[7] = (short)f2bf(b.w);
      bfr[kc] = v;
    }
    fcbias = bfc[oc];
  }

  // each lane owns batch rows (bbase + lhi*2 + r), r in {0,1}
  float cst[2], hlast[2];
#pragma unroll
  for (int r = 0; r < 2; ++r)
    cst[r] = c0[(size_t)(bbase + lhi * 2 + r) * H + jcol];

  const float*          inf = (const float*)in_;
  const unsigned short* inb = (const unsigned short*)in_;

  // lane-constant staging coordinates (valid for tid<256) + running pointers
  int srow, scol;
  if constexpr (!IN_BF16) { srow = (tid * 2) / KIN; scol = (tid * 2) % KIN; }
  else                    { srow = (tid * 4) / KIN; scol = (tid * 4) % KIN; }
  const bool sact = (srow < R);
  const int  srm  = mrow(srow & (R - 1));
  const float*          xpf = inf + (size_t)(bbase + (srow & (R - 1))) * T * KIN + scol;
  const unsigned short* xpb = inb + (size_t)(bbase + (srow & (R - 1))) * T * KIN + scol;

  unsigned short* hp = nullptr;
  if constexpr (WRITE_HOUT)
    hp = hout + (size_t)(bbase + lhi * 2) * T * H + jcol;   // r stride = T*H
  float* fp = nullptr;
  if constexpr (FUSE_FC)
    fp = fco + (size_t)(bbase + lhi * 2) * T * O + (w & 1) * 16 + l15;

  // ---- zero the whole A tile once (garbage rows stay 0 forever) ----
  for (int i = tid; i < 16 * APAD; i += 512)   // 2*16*APAD shorts = 16*APAD uints
    ((unsigned int*)Ash)[i] = 0u;
  __syncthreads();

  // ---- consumer: wait for chunks 0,1 before touching in_ ----
  if constexpr (CONS) {
    if (tid == 0) {
      while (__hip_atomic_load(flag, __ATOMIC_ACQUIRE, __HIP_MEMORY_SCOPE_AGENT) < 2)
        __builtin_amdgcn_s_sleep(4);
    }
    __syncthreads();
  }

  // ---- prologue: stage in_(0) and h0 into A[0]; preload in_(1) ----
  if (sact) {
    if constexpr (!IN_BF16) {
      float2 v = *(const float2*)xpf;
      unsigned int p = (unsigned int)f2bf(v.x) | ((unsigned int)f2bf(v.y) << 16);
      *(unsigned int*)&AEL(0, srm, scol) = p;
    } else {
      uint2 v = *(const uint2*)xpb;
      *(uint2*)&AEL(0, srm, scol) = v;
    }
  }
  {
    const int row = (tid * 4) / H, col = (tid * 4) % H;
    if (row < R) {
      float4 v = *(const float4*)(h0 + (size_t)(bbase + row) * H + col);
      uint2 p;
      p.x = (unsigned int)f2bf(v.x) | ((unsigned int)f2bf(v.y) << 16);
      p.y = (unsigned int)f2bf(v.z) | ((unsigned int)f2bf(v.w) << 16);
      *(uint2*)&AEL(0, mrow(row), KIN + col) = p;
    }
  }

  float2 pfoF; uint2 pfoB;                    // pf_old = x(t+1)
  if (sact) {
    if constexpr (!IN_BF16) pfoF = *(const float2*)(xpf + KIN);
    else                    pfoB = *(const uint2*)(xpb + KIN);
  }
  xpf += 2 * (size_t)KIN;                     // points at x(t+2)
  xpb += 2 * (size_t)KIN;
  __syncthreads();

  int cur = 0;
  for (int k = 0; k < NCH; ++k) {
    if constexpr (CONS) {
      if (k > 0) {
        const int want = (k + 2 > NCH) ? NCH : (k + 2);
        if (tid == 0) {
          while (__hip_atomic_load(flag, __ATOMIC_ACQUIRE, __HIP_MEMORY_SCOPE_AGENT) < want)
            __builtin_amdgcn_s_sleep(4);
        }
        __syncthreads();
      }
    }

    for (int tt = 0; tt < CH; ++tt) {
      const int t   = k * CH + tt;
      const int nxt = cur ^ 1;

      // issue load of x(t+2); then store x(t+1)=pf_old (its load retired a
      // full step ago -> near-zero vmcnt wait; FIFO skips the new load)
      float2 pfnF; uint2 pfnB;
      if (sact) {
        if constexpr (!IN_BF16) {
          pfnF = *(const float2*)xpf;
          unsigned int p = (unsigned int)f2bf(pfoF.x) | ((unsigned int)f2bf(pfoF.y) << 16);
          *(unsigned int*)&AEL(nxt, srm, scol) = p;
        } else {
          pfnB = *(const uint2*)xpb;
          *(uint2*)&AEL(nxt, srm, scol) = pfoB;
        }
      }

      // A-fragments (shared across this wave's 4 gate tiles + FC)
      short8 af[KC];
#pragma unroll
      for (int kc = 0; kc < KC; ++kc)
        af[kc] = *(const short8*)&AEL(cur, l15, kc * 32 + lhi * 8);

      f32x4 acc[4];
#pragma unroll
      for (int gb = 0; gb < 4; ++gb) {
        f32x4 a = {bias[gb], bias[gb], bias[gb], bias[gb]};
#pragma unroll
        for (int kc = 0; kc < KC; ++kc)
          a = __builtin_amdgcn_mfma_f32_16x16x32_bf16(af[kc], wf[gb][kc], a, 0, 0, 0);
        acc[gb] = a;
      }

      // fused FC for step t-1: h(t-1) frags are af[KC-4..KC-1]
      f32x4 fs = {fcbias, fcbias, fcbias, fcbias};
      if constexpr (FUSE_FC) {
        if (w < 2 && t > 0) {
#pragma unroll
          for (int kc = 0; kc < 4; ++kc)
            fs = __builtin_amdgcn_mfma_f32_16x16x32_bf16(af[KC - 4 + kc], bfr[kc], fs, 0, 0, 0);
        }
      }

      // elementwise: 2 valid C-rows per lane (rows lhi*4+r, batch lhi*2+r)
#pragma unroll
      for (int r = 0; r < 2; ++r) {
        float i_ = sigm(acc[0][r]);
        float f_ = sigm(acc[1][r]);
        float g_ = tanh_f(acc[2][r]);
        float o_ = sigm(acc[3][r]);
        float c_ = f_ * cst[r] + i_ * g_;
        cst[r] = c_;
        float hn = o_ * tanh_f(c_);
        hlast[r] = hn;
        unsigned short hb = f2bf(hn);
        AEL(nxt, lhi * 4 + r, KIN + jcol) = hb;
        if constexpr (WRITE_HOUT)
          hp[(size_t)r * (T * H)] = hb;
      }
      if constexpr (WRITE_HOUT) hp += H;

      if constexpr (FUSE_FC) {
        if (w < 2 && t > 0) {
          float* f0 = fp + (size_t)(t - 1) * O;
#pragma unroll
          for (int r = 0; r < 2; ++r)
            f0[(size_t)r * (T * O)] = fs[r];
        }
      }

      // LDS-only sync: global ops float across steps
      block_sync_lds();
      cur = nxt;
      if constexpr (!IN_BF16) pfoF = pfnF; else pfoB = pfnB;
      if (t < T - 3) { xpf += KIN; xpb += KIN; }
    }

    if constexpr (PROD) {
      // drain own global stores, barrier, then agent-scope release.
      __builtin_amdgcn_sched_barrier(0);
      asm volatile("s_waitcnt vmcnt(0)" ::: "memory");
      __builtin_amdgcn_s_barrier();
      if (tid == 0)
        __hip_atomic_store(flag, k + 1, __ATOMIC_RELEASE, __HIP_MEMORY_SCOPE_AGENT);
    }
  }

  // ---- tails ----
#pragma unroll
  for (int r = 0; r < 2; ++r) {
    const size_t b = bbase + lhi * 2 + r;
    hN[b * H + jcol] = hlast[r];
    cN[b * H + jcol] = cst[r];
  }
  if constexpr (FUSE_FC) {
    if (w < 2) {   // FC for final step T-1 from A[cur] h-slot = h(T-1)
      short8 a4[4];
#pragma unroll
      for (int kc = 0; kc < 4; ++kc)
        a4[kc] = *(const short8*)&AEL(cur, l15, KIN + kc * 32 + lhi * 8);
      f32x4 fs = {fcbias, fcbias, fcbias, fcbias};
#pragma unroll
      for (int kc = 0; kc < 4; ++kc)
        fs = __builtin_amdgcn_mfma_f32_16x16x32_bf16(a4[kc], bfr[kc], fs, 0, 0, 0);
      float* f0 = fp + (size_t)(T - 1) * O;
#pragma unroll
      for (int r = 0; r < 2; ++r)
        f0[(size_t)r * (T * O)] = fs[r];
    }
  }
#undef AEL
}

// ---------------------------------------------------------------------------
__global__ __launch_bounds__(512, 2) void lstm_fused(
    const float* __restrict__ x,
    const float* __restrict__ h0, const float* __restrict__ c0,
    const float* __restrict__ Wih0, const float* __restrict__ Whh0,
    const float* __restrict__ bih0, const float* __restrict__ bhh0,
    const float* __restrict__ Wih1, const float* __restrict__ Whh1,
    const float* __restrict__ bih1, const float* __restrict__ bhh1,
    const float* __restrict__ fcw, const float* __restrict__ fcb,
    unsigned short* __restrict__ out0,
    float* __restrict__ out, float* __restrict__ hN, float* __restrict__ cN,
    int* __restrict__ flags)
{
  __shared__ __align__(16) unsigned short Ash[2 * 16 * 264];
  const int bid = blockIdx.x;
  if (bid < NBL) {
    // L0 producer
    scan_body<64, false, true, false, true, false>(
        Ash, x, h0, c0, Wih0, Whh0, bih0, bhh0,
        out0, hN, cN, nullptr, nullptr, nullptr,
        flags + bid, bid * R);
  } else {
    // L1 consumer + fused FC
    const int rb = bid - NBL;
    scan_body<128, true, false, true, false, true>(
        Ash, out0, h0 + B * H, c0 + B * H, Wih1, Whh1, bih1, bhh1,
        nullptr, hN + B * H, cN + B * H, fcw, fcb, out,
        flags + rb, rb * R);
  }
}

// ---------------------------------------------------------------------------
extern "C" void kernel_launch(void* const* d_in, const int* in_sizes, int n_in,
                              void* d_out, int out_size, void* d_ws, size_t ws_size,
                              hipStream_t stream) {
  (void)in_sizes; (void)n_in; (void)out_size; (void)ws_size;

  const float* x    = (const float*)d_in[0];
  const float* h0   = (const float*)d_in[1];
  const float* c0   = (const float*)d_in[2];
  const float* Wih0 = (const float*)d_in[3];
  const float* Whh0 = (const float*)d_in[4];
  const float* bih0 = (const float*)d_in[5];
  const float* bhh0 = (const float*)d_in[6];
  const float* Wih1 = (const float*)d_in[7];
  const float* Whh1 = (const float*)d_in[8];
  const float* bih1 = (const float*)d_in[9];
  const float* bhh1 = (const float*)d_in[10];
  const float* fcw  = (const float*)d_in[11];
  const float* fcb  = (const float*)d_in[12];

  int*            flags = (int*)d_ws;                             // 32 ints
  unsigned short* out0  = (unsigned short*)((char*)d_ws + 1024);  // bf16 [B,T,H]

  float* out = (float*)d_out;                                     // [B,T,32]
  float* hN  = out + (size_t)B * T * O;                           // [2,B,H]
  float* cN  = hN + (size_t)2 * B * H;                            // [2,B,H]

  hipMemsetAsync(d_ws, 0, 1024, stream);   // reset pipeline flags every launch
  lstm_fused<<<2 * NBL, 512, 0, stream>>>(
      x, h0, c0, Wih0, Whh0, bih0, bhh0, Wih1, Whh1, bih1, bhh1,
      fcw, fcb, out0, out, hN, cN, flags);
}

// Round 6
// 766.171 us; speedup vs baseline: 2.8934x; 1.2772x over previous
//
#include <hip/hip_runtime.h>

// ---------------------------------------------------------------------------
// 2-layer LSTM (B=256,T=1024,in=64,H=128) + fused FC(128->32), bf16 MFMA.
// Layer-pipelined: 128 blocks = 64 L0 + 64 L1 concurrent; L1 lags L0 by 2
// chunks (CH=16), handoff via global out0 + agent-scope release/acquire.
// R6: (a) x-contribution precomputed one step ahead (accX pipeline) -> gate
// MFMA dep chain halves (K=128 recurrent part only), x-MFMAs overlap EW;
// (b) R=4 rows/block, batch row b -> tile row 4b: exactly 1 EW row per lane
// (10 trans/lane/step), uniform, no divergence.
// ---------------------------------------------------------------------------

static constexpr int B   = 256;
static constexpr int T   = 1024;
static constexpr int H   = 128;
static constexpr int O   = 32;
static constexpr int R   = 4;         // batch rows per block
static constexpr int NBL = B / R;     // 64 blocks per layer
static constexpr int CH  = 16;        // steps per pipeline chunk
static constexpr int NCH = T / CH;

typedef __attribute__((ext_vector_type(8))) short  short8;
typedef __attribute__((ext_vector_type(4))) float  f32x4;

#define LOG2E 1.4426950408889634f

#if __has_builtin(__builtin_amdgcn_exp2f)
#define EXP2(x) __builtin_amdgcn_exp2f(x)
#else
#define EXP2(x) __expf((x) * 0.69314718056f)
#endif
#if __has_builtin(__builtin_amdgcn_rcpf)
#define RCP(x) __builtin_amdgcn_rcpf(x)
#else
#define RCP(x) (1.0f / (x))
#endif

__device__ __forceinline__ unsigned short f2bf(float f) {
  unsigned int u = __builtin_bit_cast(unsigned int, f);
  u += 0x7fffu + ((u >> 16) & 1u);        // round-to-nearest-even
  return (unsigned short)(u >> 16);
}

__device__ __forceinline__ float sigm(float x) {
  return RCP(1.0f + EXP2(-LOG2E * x));
}
__device__ __forceinline__ float tanh_f(float x) {
  return 1.0f - 2.0f * RCP(1.0f + EXP2(2.0f * LOG2E * x));
}

// LDS-only barrier: wait own ds ops, then s_barrier. Global ops float.
__device__ __forceinline__ void block_sync_lds() {
  __builtin_amdgcn_sched_barrier(0);
  asm volatile("s_waitcnt lgkmcnt(0)" ::: "memory");
  __builtin_amdgcn_s_barrier();
  __builtin_amdgcn_sched_barrier(0);
}

// ---------------------------------------------------------------------------
// One layer's full-T scan for R=4 batch rows. 8 waves; wave w owns gate cols
// [w*16,w*16+16) of each gate block (i,f,g,o). Lane owns 1 C-row (reg 0).
// LDS buffer A[buf] at iter t holds {h(t-1), x(t+1)}; accX = bias + x@Wih is
// computed one step ahead; gates = mfma(h, Whh, C=accX).
// PROD: drain + flag per CH steps. CONS: wait flag>=k+2.
// FUSE_FC (L1): waves 0,1 emit out[.,t-1,.] from h(t-1) frags each step.
// ---------------------------------------------------------------------------
template <int KIN, bool IN_BF16, bool WRITE_HOUT, bool FUSE_FC, bool PROD, bool CONS>
__device__ __forceinline__ void scan_body(
    unsigned short* __restrict__ Ash,
    const void* __restrict__ in_,            // [B,T,KIN] f32 (L0) / bf16 (L1)
    const float* __restrict__ h0,            // [B,H] layer slice
    const float* __restrict__ c0,            // [B,H] layer slice
    const float* __restrict__ Wih,           // [4H,KIN]
    const float* __restrict__ Whh,           // [4H,H]
    const float* __restrict__ bih,           // [4H]
    const float* __restrict__ bhh,           // [4H]
    unsigned short* __restrict__ hout,       // bf16 [B,T,H] (L0 only)
    float* __restrict__ hN,                  // [B,H]
    float* __restrict__ cN,                  // [B,H]
    const float* __restrict__ Wfc,           // [32,128] (L1 only)
    const float* __restrict__ bfc,           // [32]
    float* __restrict__ fco,                 // [B,T,32]
    int* __restrict__ flag, const int bbase)
{
  constexpr int AK   = KIN + H;              // 192 or 256
  constexpr int KCX  = KIN / 32;             // 2 or 4
  constexpr int KCH  = H / 32;               // 4
  constexpr int APAD = AK + 8;

  const int tid  = threadIdx.x;
  const int w    = tid >> 6;
  const int l    = tid & 63;
  const int l15  = l & 15;
  const int lhi  = l >> 4;
  const int jcol = w * 16 + l15;

#define AEL(buf, row, col) Ash[(((buf) * 16 + (row)) * APAD) + (col)]

  // ---- gate-weight fragments, split x-part / h-part ----
  short8 wfx[4][KCX], wfh[4][KCH];
  float  bias4[4];
#pragma unroll
  for (int gb = 0; gb < 4; ++gb) {
    const int gc = gb * H + jcol;
    const float* wi = Wih + (size_t)gc * KIN;
    const float* wh = Whh + (size_t)gc * H;
#pragma unroll
    for (int kc = 0; kc < KCX; ++kc) {
      const float* s = wi + kc * 32 + lhi * 8;
      float4 a = *(const float4*)s;
      float4 b = *(const float4*)(s + 4);
      short8 v;
      v[0] = (short)f2bf(a.x); v[1] = (short)f2bf(a.y);
      v[2] = (short)f2bf(a.z); v[3] = (short)f2bf(a.w);
      v[4] = (short)f2bf(b.x); v[5] = (short)f2bf(b.y);
      v[6] = (short)f2bf(b.z); v[7] = (short)f2bf(b.w);
      wfx[gb][kc] = v;
    }
#pragma unroll
    for (int kc = 0; kc < KCH; ++kc) {
      const float* s = wh + kc * 32 + lhi * 8;
      float4 a = *(const float4*)s;
      float4 b = *(const float4*)(s + 4);
      short8 v;
      v[0] = (short)f2bf(a.x); v[1] = (short)f2bf(a.y);
      v[2] = (short)f2bf(a.z); v[3] = (short)f2bf(a.w);
      v[4] = (short)f2bf(b.x); v[5] = (short)f2bf(b.y);
      v[6] = (short)f2bf(b.z); v[7] = (short)f2bf(b.w);
      wfh[gb][kc] = v;
    }
    bias4[gb] = bih[gc] + bhh[gc];
  }

  // ---- FC weight fragments (waves 0,1) ----
  short8 bfr[4];
  float fcbias = 0.f;
  if constexpr (FUSE_FC) {
    const int oc = (w & 1) * 16 + l15;
#pragma unroll
    for (int kc = 0; kc < 4; ++kc) {
      const float* s = Wfc + (size_t)oc * H + kc * 32 + lhi * 8;
      float4 a = *(const float4*)s;
      float4 b = *(const float4*)(s + 4);
      short8 v;
      v[0] = (short)f2bf(a.x); v[1] = (short)f2bf(a.y);
      v[2] = (short)f2bf(a.z); v[3] = (short)f2bf(a.w);
      v[4] = (short)f2bf(b.x); v[5] = (short)f2bf(b.y);
      v[6] = (short)f2bf(b.z); v[7] = (short)f2bf(b.w);
      bfr[kc] = v;
    }
    fcbias = bfc[oc];
  }

  // lane owns batch row (bbase + lhi), tile row lhi*4, acc reg 0
  float cst   = c0[(size_t)(bbase + lhi) * H + jcol];
  float hlast = 0.f;

  const float*          inf = (const float*)in_;
  const unsigned short* inb = (const unsigned short*)in_;

  // staging coords: 128 lanes, 32 lanes/row
  const bool sact = tid < 128;
  const int  srow = (tid >> 5) & 3;
  int scol;
  if constexpr (!IN_BF16) scol = (tid * 2) & 63;
  else                    scol = (tid * 4) & 127;
  const int srm = srow * 4;                  // tile row = 4*b
  const float*          xpf = inf + (size_t)(bbase + srow) * T * KIN + scol;
  const unsigned short* xpb = inb + (size_t)(bbase + srow) * T * KIN + scol;

  unsigned short* hp = nullptr;
  if constexpr (WRITE_HOUT)
    hp = hout + (size_t)(bbase + lhi) * T * H + jcol;
  float* fp = nullptr;
  if constexpr (FUSE_FC)
    fp = fco + (size_t)(bbase + lhi) * T * O + (w & 1) * 16 + l15;

  // ---- zero both A buffers once (garbage rows stay 0 forever) ----
  for (int i = tid; i < 16 * APAD; i += 512)
    ((unsigned int*)Ash)[i] = 0u;
  __syncthreads();

  // ---- consumer: wait for chunks 0,1 before touching in_ ----
  if constexpr (CONS) {
    if (tid == 0) {
      while (__hip_atomic_load(flag, __ATOMIC_ACQUIRE, __HIP_MEMORY_SCOPE_AGENT) < 2)
        __builtin_amdgcn_s_sleep(4);
    }
    __syncthreads();
  }

  // ---- prologue ----
  // A[1].x <- x(0) (consumed below for accX_0);  A[0].x <- x(1);  A[0].h <- h0
  if (sact) {
    if constexpr (!IN_BF16) {
      float2 v0 = *(const float2*)xpf;
      float2 v1 = *(const float2*)(xpf + KIN);
      *(unsigned int*)&AEL(1, srm, scol) =
          (unsigned int)f2bf(v0.x) | ((unsigned int)f2bf(v0.y) << 16);
      *(unsigned int*)&AEL(0, srm, scol) =
          (unsigned int)f2bf(v1.x) | ((unsigned int)f2bf(v1.y) << 16);
    } else {
      uint2 v0 = *(const uint2*)xpb;
      uint2 v1 = *(const uint2*)(xpb + KIN);
      *(uint2*)&AEL(1, srm, scol) = v0;
      *(uint2*)&AEL(0, srm, scol) = v1;
    }
  }
  if (tid < 128) {
    const int row = tid >> 5, col = (tid * 4) & 127;
    float4 v = *(const float4*)(h0 + (size_t)(bbase + row) * H + col);
    uint2 p;
    p.x = (unsigned int)f2bf(v.x) | ((unsigned int)f2bf(v.y) << 16);
    p.y = (unsigned int)f2bf(v.z) | ((unsigned int)f2bf(v.w) << 16);
    *(uint2*)&AEL(0, row * 4, KIN + col) = p;
  }

  float2 pfoF = {0.f, 0.f}; uint2 pfoB = {0u, 0u};   // holds x(t+2) at iter t
  if (sact) {
    if constexpr (!IN_BF16) pfoF = *(const float2*)(xpf + 2 * (size_t)KIN);
    else                    pfoB = *(const uint2*)(xpb + 2 * (size_t)KIN);
  }
  xpf += 3 * (size_t)KIN;                            // points at x(3)
  xpb += 3 * (size_t)KIN;
  __syncthreads();

  // accX_0 = bias + x(0) @ Wih^T  (x(0) frags from A[1].x)
  f32x4 accX[4];
  {
    short8 afx[KCX];
#pragma unroll
    for (int kc = 0; kc < KCX; ++kc)
      afx[kc] = *(const short8*)&AEL(1, l15, kc * 32 + lhi * 8);
#pragma unroll
    for (int gb = 0; gb < 4; ++gb) {
      f32x4 a = {bias4[gb], bias4[gb], bias4[gb], bias4[gb]};
#pragma unroll
      for (int kc = 0; kc < KCX; ++kc)
        a = __builtin_amdgcn_mfma_f32_16x16x32_bf16(afx[kc], wfx[gb][kc], a, 0, 0, 0);
      accX[gb] = a;
    }
  }
  __syncthreads();   // protect A[1].x (just read) from iter-0 writes

  int cur = 0;
  for (int k = 0; k < NCH; ++k) {
    if constexpr (CONS) {
      if (k > 0) {
        const int want = (k + 2 > NCH) ? NCH : (k + 2);
        if (tid == 0) {
          while (__hip_atomic_load(flag, __ATOMIC_ACQUIRE, __HIP_MEMORY_SCOPE_AGENT) < want)
            __builtin_amdgcn_s_sleep(4);
        }
        __syncthreads();
      }
    }

    for (int tt = 0; tt < CH; ++tt) {
      const int t   = k * CH + tt;
      const int nxt = cur ^ 1;

      // issue load of x(t+3); store x(t+2)=pf_old (load retired a step ago)
      float2 pfnF = {0.f, 0.f}; uint2 pfnB = {0u, 0u};
      if (sact) {
        if constexpr (!IN_BF16) {
          pfnF = *(const float2*)xpf;
          *(unsigned int*)&AEL(nxt, srm, scol) =
              (unsigned int)f2bf(pfoF.x) | ((unsigned int)f2bf(pfoF.y) << 16);
        } else {
          pfnB = *(const uint2*)xpb;
          *(uint2*)&AEL(nxt, srm, scol) = pfoB;
        }
      }

      // h(t-1) fragments, then x(t+1) fragments (reads pipeline together)
      short8 afh[KCH];
#pragma unroll
      for (int kc = 0; kc < KCH; ++kc)
        afh[kc] = *(const short8*)&AEL(cur, l15, KIN + kc * 32 + lhi * 8);
      short8 afx[KCX];
#pragma unroll
      for (int kc = 0; kc < KCX; ++kc)
        afx[kc] = *(const short8*)&AEL(cur, l15, kc * 32 + lhi * 8);

      // gates(t) = accX(t) + h(t-1) @ Whh^T   (4-deep dependent chain)
      f32x4 acc[4];
#pragma unroll
      for (int gb = 0; gb < 4; ++gb) {
        f32x4 a = accX[gb];
#pragma unroll
        for (int kc = 0; kc < KCH; ++kc)
          a = __builtin_amdgcn_mfma_f32_16x16x32_bf16(afh[kc], wfh[gb][kc], a, 0, 0, 0);
        acc[gb] = a;
      }

      // fused FC for step t-1 from h(t-1) frags
      f32x4 fs = {fcbias, fcbias, fcbias, fcbias};
      if constexpr (FUSE_FC) {
        if (w < 2 && t > 0) {
#pragma unroll
          for (int kc = 0; kc < 4; ++kc)
            fs = __builtin_amdgcn_mfma_f32_16x16x32_bf16(afh[kc], bfr[kc], fs, 0, 0, 0);
        }
      }

      // elementwise: single row per lane (tile row lhi*4, batch bbase+lhi)
      {
        float i_ = sigm(acc[0][0]);
        float f_ = sigm(acc[1][0]);
        float g_ = tanh_f(acc[2][0]);
        float o_ = sigm(acc[3][0]);
        float c_ = f_ * cst + i_ * g_;
        cst = c_;
        float hn = o_ * tanh_f(c_);
        hlast = hn;
        unsigned short hb = f2bf(hn);
        AEL(nxt, lhi * 4, KIN + jcol) = hb;
        if constexpr (WRITE_HOUT) { hp[0] = hb; }
      }
      if constexpr (WRITE_HOUT) hp += H;

      if constexpr (FUSE_FC) {
        if (w < 2 && t > 0)
          fp[(size_t)(t - 1) * O] = fs[0];
      }

      // accX(t+1) = bias + x(t+1) @ Wih^T  (independent of EW; fills pipe)
#pragma unroll
      for (int gb = 0; gb < 4; ++gb) {
        f32x4 a = {bias4[gb], bias4[gb], bias4[gb], bias4[gb]};
#pragma unroll
        for (int kc = 0; kc < KCX; ++kc)
          a = __builtin_amdgcn_mfma_f32_16x16x32_bf16(afx[kc], wfx[gb][kc], a, 0, 0, 0);
        accX[gb] = a;
      }

      // LDS-only sync: global ops float across steps
      block_sync_lds();
      cur = nxt;
      if constexpr (!IN_BF16) pfoF = pfnF; else pfoB = pfnB;
      if (t <= T - 5) { xpf += KIN; xpb += KIN; }
    }

    if constexpr (PROD) {
      // drain own global stores, barrier, then agent-scope release.
      __builtin_amdgcn_sched_barrier(0);
      asm volatile("s_waitcnt vmcnt(0)" ::: "memory");
      __builtin_amdgcn_s_barrier();
      if (tid == 0)
        __hip_atomic_store(flag, k + 1, __ATOMIC_RELEASE, __HIP_MEMORY_SCOPE_AGENT);
    }
  }

  // ---- tails ----
  {
    const size_t b = bbase + lhi;
    hN[b * H + jcol] = hlast;
    cN[b * H + jcol] = cst;
  }
  if constexpr (FUSE_FC) {
    if (w < 2) {   // FC for final step T-1 from A[cur] h-slot = h(T-1)
      short8 a4[4];
#pragma unroll
      for (int kc = 0; kc < 4; ++kc)
        a4[kc] = *(const short8*)&AEL(cur, l15, KIN + kc * 32 + lhi * 8);
      f32x4 fs = {fcbias, fcbias, fcbias, fcbias};
#pragma unroll
      for (int kc = 0; kc < 4; ++kc)
        fs = __builtin_amdgcn_mfma_f32_16x16x32_bf16(a4[kc], bfr[kc], fs, 0, 0, 0);
      fp[(size_t)(T - 1) * O] = fs[0];
    }
  }
#undef AEL
}

// ---------------------------------------------------------------------------
__global__ __launch_bounds__(512, 2) void lstm_fused(
    const float* __restrict__ x,
    const float* __restrict__ h0, const float* __restrict__ c0,
    const float* __restrict__ Wih0, const float* __restrict__ Whh0,
    const float* __restrict__ bih0, const float* __restrict__ bhh0,
    const float* __restrict__ Wih1, const float* __restrict__ Whh1,
    const float* __restrict__ bih1, const float* __restrict__ bhh1,
    const float* __restrict__ fcw, const float* __restrict__ fcb,
    unsigned short* __restrict__ out0,
    float* __restrict__ out, float* __restrict__ hN, float* __restrict__ cN,
    int* __restrict__ flags)
{
  __shared__ __align__(16) unsigned short Ash[2 * 16 * 264];
  const int bid = blockIdx.x;
  if (bid < NBL) {
    // L0 producer
    scan_body<64, false, true, false, true, false>(
        Ash, x, h0, c0, Wih0, Whh0, bih0, bhh0,
        out0, hN, cN, nullptr, nullptr, nullptr,
        flags + bid, bid * R);
  } else {
    // L1 consumer + fused FC
    const int rb = bid - NBL;
    scan_body<128, true, false, true, false, true>(
        Ash, out0, h0 + B * H, c0 + B * H, Wih1, Whh1, bih1, bhh1,
        nullptr, hN + B * H, cN + B * H, fcw, fcb, out,
        flags + rb, rb * R);
  }
}

// ---------------------------------------------------------------------------
extern "C" void kernel_launch(void* const* d_in, const int* in_sizes, int n_in,
                              void* d_out, int out_size, void* d_ws, size_t ws_size,
                              hipStream_t stream) {
  (void)in_sizes; (void)n_in; (void)out_size; (void)ws_size;

  const float* x    = (const float*)d_in[0];
  const float* h0   = (const float*)d_in[1];
  const float* c0   = (const float*)d_in[2];
  const float* Wih0 = (const float*)d_in[3];
  const float* Whh0 = (const float*)d_in[4];
  const float* bih0 = (const float*)d_in[5];
  const float* bhh0 = (const float*)d_in[6];
  const float* Wih1 = (const float*)d_in[7];
  const float* Whh1 = (const float*)d_in[8];
  const float* bih1 = (const float*)d_in[9];
  const float* bhh1 = (const float*)d_in[10];
  const float* fcw  = (const float*)d_in[11];
  const float* fcb  = (const float*)d_in[12];

  int*            flags = (int*)d_ws;                             // 64 ints
  unsigned short* out0  = (unsigned short*)((char*)d_ws + 1024);  // bf16 [B,T,H]

  float* out = (float*)d_out;                                     // [B,T,32]
  float* hN  = out + (size_t)B * T * O;                           // [2,B,H]
  float* cN  = hN + (size_t)2 * B * H;                            // [2,B,H]

  hipMemsetAsync(d_ws, 0, 1024, stream);   // reset pipeline flags every launch
  lstm_fused<<<2 * NBL, 512, 0, stream>>>(
      x, h0, c0, Wih0, Whh0, bih0, bhh0, Wih1, Whh1, bih1, bhh1,
      fcw, fcb, out0, out, hN, cN, flags);
}